// Round 11
// baseline (166.118 us; speedup 1.0000x reference)
//
#include <hip/hip_runtime.h>
#include <hip/hip_bf16.h>

// Problem constants
#define Bv 4
#define Sv 4096
#define Dv 1024
#define Hv 16
#define Ov 64
#define NCv 64
#define BHv 64

typedef __attribute__((ext_vector_type(8))) short bf16x8;
typedef __attribute__((ext_vector_type(4))) unsigned short u16x4;
typedef __attribute__((ext_vector_type(8))) unsigned short u16x8;
typedef __attribute__((ext_vector_type(4))) float f32x4;
#define MFMA(a, b, c) __builtin_amdgcn_mfma_f32_16x16x32_bf16(a, b, c, 0, 0, 0)

__device__ __forceinline__ unsigned short f2bs(float f) {
  union { __hip_bfloat16 h; unsigned short u; } v;
  v.h = __float2bfloat16(f);
  return v.u;
}
__device__ __forceinline__ float b2f(unsigned short u) {
  union { unsigned u; float f; } v; v.u = ((unsigned)u) << 16; return v.f;
}
__device__ __forceinline__ float elu1(float a) {
  return a > 0.f ? a + 1.f : __expf(a);
}
__device__ __forceinline__ f32x4 zero4() {
  f32x4 v = {0.f, 0.f, 0.f, 0.f}; return v;
}
__device__ __forceinline__ bf16x8 pack8(float4 a, float4 b) {
  union { u16x8 u; bf16x8 h; } r;
  r.u[0] = f2bs(a.x); r.u[1] = f2bs(a.y); r.u[2] = f2bs(a.z); r.u[3] = f2bs(a.w);
  r.u[4] = f2bs(b.x); r.u[5] = f2bs(b.y); r.u[6] = f2bs(b.z); r.u[7] = f2bs(b.w);
  return r.h;
}

// ---------------------------------------------------------------------------
// K0 prep: Wq/Wk/Wv [h][d][o] -> bf16 [h][o][d]; Wp [d][o2] -> bf16 [o2][d]
// ---------------------------------------------------------------------------
__global__ __launch_bounds__(256) void k_prep_w(
    const float* __restrict__ Wq, const float* __restrict__ Wk,
    const float* __restrict__ Wv, const float* __restrict__ Wp,
    unsigned short* __restrict__ wqT, unsigned short* __restrict__ wkT,
    unsigned short* __restrict__ wvT, unsigned short* __restrict__ wpT)
{
  const int blk = blockIdx.x, tid = threadIdx.x;
  if (blk < 16) {
    int h = blk;
    for (int j = tid; j < 4096; j += 256) {       // j = o*64 + d (output idx)
      int o = j >> 6, d = j & 63;
      int src = h * 4096 + d * 64 + o;
      wqT[h * 4096 + j] = f2bs(Wq[src]);
      wkT[h * 4096 + j] = f2bs(Wk[src]);
      wvT[h * 4096 + j] = f2bs(Wv[src]);
    }
  } else {
    int b2 = blk - 16;
#pragma unroll
    for (int k = 0; k < 4; ++k) {
      int j = b2 * 1024 + tid + k * 256;          // j = o2*1024 + d
      int o = j >> 10, d = j & 1023;
      wpT[j] = f2bs(Wp[d * 64 + o]);
    }
  }
}

// ---------------------------------------------------------------------------
// K1: per (bh,chunk): K=elu1(x Wk), V=x Wv
//   publishes ONLY: mir [o][e] = (K^T V)^T bf16, zmir [e] bf16  (34 MB total)
// ---------------------------------------------------------------------------
__global__ __launch_bounds__(256) void k_chunk_state(
    const float* __restrict__ x, const unsigned short* __restrict__ wkT,
    const unsigned short* __restrict__ wvT, unsigned short* __restrict__ mir,
    unsigned short* __restrict__ zmir)
{
  __shared__ __align__(16) unsigned short kT[64][72];     // K^T[e][t]
  __shared__ __align__(16) unsigned short vT[64][72];     // V^T[o][t]
  __shared__ float zpart[4][64];

  const int tid = threadIdx.x, blk = blockIdx.x;
  const int c = blk & 63, bh = blk >> 6, h = bh & 15, b = bh >> 4;
  const int lane = tid & 63, w = tid >> 6;
  const int ll = lane & 15, hl = lane >> 4;

  const float* xr = x + ((size_t)(b * Sv + c * 64 + w * 16 + ll)) * 1024 + h * 64;
  float4 f0 = *(const float4*)(xr + hl * 8);
  float4 f1 = *(const float4*)(xr + hl * 8 + 4);
  float4 f2 = *(const float4*)(xr + 32 + hl * 8);
  float4 f3 = *(const float4*)(xr + 32 + hl * 8 + 4);
  const bf16x8 xa0 = pack8(f0, f1);
  const bf16x8 xa1 = pack8(f2, f3);

  // K = elu1(x Wk) -> kT + zpart
  const unsigned short* wk = wkT + h * 4096;
#pragma unroll
  for (int ct = 0; ct < 4; ++ct) {
    bf16x8 b0 = *(const bf16x8*)(wk + (ct * 16 + ll) * 64 + hl * 8);
    bf16x8 b1 = *(const bf16x8*)(wk + (ct * 16 + ll) * 64 + 32 + hl * 8);
    f32x4 a = zero4(); a = MFMA(xa0, b0, a); a = MFMA(xa1, b1, a);
    u16x4 p; float part = 0.f;
#pragma unroll
    for (int r = 0; r < 4; ++r) {
      float kv = elu1(a[r]); part += kv;
      p[r] = f2bs(kv);
    }
    *(u16x4*)&kT[ct * 16 + ll][w * 16 + hl * 4] = p;
    part += __shfl_xor(part, 16);
    part += __shfl_xor(part, 32);
    if (hl == 0) zpart[w][ct * 16 + ll] = part;
  }
  // V = x Wv -> vT[o][t]
  const unsigned short* wv = wvT + h * 4096;
#pragma unroll
  for (int ct = 0; ct < 4; ++ct) {
    bf16x8 b0 = *(const bf16x8*)(wv + (ct * 16 + ll) * 64 + hl * 8);
    bf16x8 b1 = *(const bf16x8*)(wv + (ct * 16 + ll) * 64 + 32 + hl * 8);
    f32x4 a = zero4(); a = MFMA(xa0, b0, a); a = MFMA(xa1, b1, a);
    u16x4 p;
#pragma unroll
    for (int r = 0; r < 4; ++r) p[r] = f2bs(a[r]);
    *(u16x4*)&vT[ct * 16 + ll][w * 16 + hl * 4] = p;
  }
  __syncthreads();

  // KtV: C[e][o]; write transposed [o][e] to mir
  const bf16x8 ka0 = *(const bf16x8*)&kT[w * 16 + ll][hl * 8];
  const bf16x8 ka1 = *(const bf16x8*)&kT[w * 16 + ll][32 + hl * 8];
  unsigned short* mp = mir + (size_t)blk * 4096;
#pragma unroll
  for (int ct = 0; ct < 4; ++ct) {
    bf16x8 v0 = *(const bf16x8*)&vT[ct * 16 + ll][hl * 8];
    bf16x8 v1 = *(const bf16x8*)&vT[ct * 16 + ll][32 + hl * 8];
    f32x4 s = zero4(); s = MFMA(ka0, v0, s); s = MFMA(ka1, v1, s);
    u16x4 p;
#pragma unroll
    for (int r = 0; r < 4; ++r) p[r] = f2bs(s[r]);
    *(u16x4*)&mp[(ct * 16 + ll) * 64 + w * 16 + hl * 4] = p;
  }
  if (tid < 64)
    zmir[(size_t)blk * 64 + tid] = f2bs(
        zpart[0][tid] + zpart[1][tid] + zpart[2][tid] + zpart[3][tid]);
}

// ---------------------------------------------------------------------------
// K2: exclusive prefix over chunks — loads up-front, register scan, stores.
// ---------------------------------------------------------------------------
__global__ __launch_bounds__(256) void k_prefix(
    unsigned short* __restrict__ mir, unsigned short* __restrict__ zmir)
{
  const int bh = blockIdx.x / 17, g = blockIdx.x % 17;
  const int tid = threadIdx.x;
  if (g < 16) {
    size_t base = (size_t)bh * 64 * 4096 + g * 256 + tid;
    unsigned short v[64];
#pragma unroll
    for (int cc = 0; cc < 64; ++cc) v[cc] = mir[base + (size_t)cc * 4096];
    float carry = 0.f;
#pragma unroll
    for (int cc = 0; cc < 64; ++cc) {
      float f = b2f(v[cc]);
      v[cc] = f2bs(carry);
      carry += f;
    }
#pragma unroll
    for (int cc = 0; cc < 64; ++cc) mir[base + (size_t)cc * 4096] = v[cc];
  } else if (tid < 64) {
    size_t base = (size_t)bh * 64 * 64 + tid;
    unsigned short v[64];
#pragma unroll
    for (int cc = 0; cc < 64; ++cc) v[cc] = zmir[base + (size_t)cc * 64];
    float carry = 0.f;
#pragma unroll
    for (int cc = 0; cc < 64; ++cc) {
      float f = b2f(v[cc]);
      v[cc] = f2bs(carry);
      carry += f;
    }
#pragma unroll
    for (int cc = 0; cc < 64; ++cc) zmir[base + (size_t)cc * 64] = v[cc];
  }
}

// ---------------------------------------------------------------------------
// K3: per (b,h,chunk) — ONE head per block, TWO LDS buffers (18.4 KB):
//   B1: Q-stage -> K -> A-stage -> y-stage    B2: V^T
//   y_h = (Q Sprev + tril(Q K^T) V) / (q.zprev + rowsum + eps)
// Barrier 1: after K/V staged. Barrier 2: after QK^T (K fully consumed),
// before A overwrites B1 stripes. All stripe reuse is wave-private.
// ---------------------------------------------------------------------------
__global__ __launch_bounds__(256, 8) void k_y(
    const float* __restrict__ x, const unsigned short* __restrict__ wqT,
    const unsigned short* __restrict__ wkT, const unsigned short* __restrict__ wvT,
    const unsigned short* __restrict__ mir, const unsigned short* __restrict__ zmir,
    unsigned short* __restrict__ y)
{
  __shared__ __align__(16) unsigned short B1[64][72];  // Q / K / A / y
  __shared__ __align__(16) unsigned short B2[64][72];  // V^T[o][t]

  const int tid = threadIdx.x, blk = blockIdx.x;
  const int c = blk & 63, bh = blk >> 6, h = bh & 15, b = bh >> 4;
  const int lane = tid & 63, w = tid >> 6;
  const int ll = lane & 15, hl = lane >> 4;
  const size_t sblk = (size_t)blk;

  // early independent loads: zprev
  const unsigned short* zp = zmir + sblk * 64;
  u16x8 zz0 = *(const u16x8*)(zp + hl * 8);
  u16x8 zz1 = *(const u16x8*)(zp + 32 + hl * 8);

  // x slice (second read; L3-hot)
  const float* xr = x + ((size_t)(b * Sv + c * 64 + w * 16 + ll)) * 1024 + h * 64;
  float4 f0 = *(const float4*)(xr + hl * 8);
  float4 f1 = *(const float4*)(xr + hl * 8 + 4);
  float4 f2 = *(const float4*)(xr + 32 + hl * 8);
  float4 f3 = *(const float4*)(xr + 32 + hl * 8 + 4);
  const bf16x8 xa0 = pack8(f0, f1);
  const bf16x8 xa1 = pack8(f2, f3);

  // ---- Q ladder -> B1 own stripe -> immediate readback (in-wave order) ----
  const unsigned short* wq = wqT + h * 4096;
#pragma unroll
  for (int ct = 0; ct < 4; ++ct) {
    bf16x8 b0 = *(const bf16x8*)(wq + (ct * 16 + ll) * 64 + hl * 8);
    bf16x8 b1 = *(const bf16x8*)(wq + (ct * 16 + ll) * 64 + 32 + hl * 8);
    f32x4 a = zero4(); a = MFMA(xa0, b0, a); a = MFMA(xa1, b1, a);
#pragma unroll
    for (int r = 0; r < 4; ++r)
      B1[w * 16 + hl * 4 + r][ct * 16 + ll] = f2bs(elu1(a[r]));
  }
  const bf16x8 qa0 = *(const bf16x8*)&B1[w * 16 + ll][hl * 8];
  const bf16x8 qa1 = *(const bf16x8*)&B1[w * 16 + ll][32 + hl * 8];

  // den0 = q . zprev (registers only)
  float den0 = 0.f;
  {
    const u16x8 qu0 = *(const u16x8*)&qa0;
    const u16x8 qu1 = *(const u16x8*)&qa1;
#pragma unroll
    for (int i = 0; i < 8; ++i) {
      den0 += b2f(qu0[i]) * b2f(zz0[i]);
      den0 += b2f(qu1[i]) * b2f(zz1[i]);
    }
    den0 += __shfl_xor(den0, 16);
    den0 += __shfl_xor(den0, 32);
  }

  // ---- K ladder -> B1 own stripe (overwrites Q stage; in-wave WAR safe) ----
  const unsigned short* wk = wkT + h * 4096;
#pragma unroll
  for (int ct = 0; ct < 4; ++ct) {
    bf16x8 b0 = *(const bf16x8*)(wk + (ct * 16 + ll) * 64 + hl * 8);
    bf16x8 b1 = *(const bf16x8*)(wk + (ct * 16 + ll) * 64 + 32 + hl * 8);
    f32x4 a = zero4(); a = MFMA(xa0, b0, a); a = MFMA(xa1, b1, a);
#pragma unroll
    for (int r = 0; r < 4; ++r)
      B1[w * 16 + hl * 4 + r][ct * 16 + ll] = f2bs(elu1(a[r]));
  }
  // ---- V ladder -> B2 as V^T[o][t] (packed b64 column writes) ----
  const unsigned short* wv = wvT + h * 4096;
#pragma unroll
  for (int ct = 0; ct < 4; ++ct) {
    bf16x8 b0 = *(const bf16x8*)(wv + (ct * 16 + ll) * 64 + hl * 8);
    bf16x8 b1 = *(const bf16x8*)(wv + (ct * 16 + ll) * 64 + 32 + hl * 8);
    f32x4 a = zero4(); a = MFMA(xa0, b0, a); a = MFMA(xa1, b1, a);
    u16x4 p;
#pragma unroll
    for (int r = 0; r < 4; ++r) p[r] = f2bs(a[r]);
    *(u16x4*)&B2[ct * 16 + ll][w * 16 + hl * 4] = p;
  }
  __syncthreads();   // barrier 1: K (B1) and V^T (B2) visible to all waves

  // ---- QS (global mir) interleaved with QK^T (LDS K) for ILP ----
  const unsigned short* sp = mir + sblk * 4096;
  f32x4 nacc[4], aacc[4];
#pragma unroll
  for (int ct = 0; ct < 4; ++ct) {
    bf16x8 s0 = *(const bf16x8*)(sp + (ct * 16 + ll) * 64 + hl * 8);
    bf16x8 s1 = *(const bf16x8*)(sp + (ct * 16 + ll) * 64 + 32 + hl * 8);
    f32x4 n = zero4(); n = MFMA(qa0, s0, n); n = MFMA(qa1, s1, n);
    nacc[ct] = n;
    if (ct <= w) {   // wave-uniform
      bf16x8 b0 = *(const bf16x8*)&B1[ct * 16 + ll][hl * 8];
      bf16x8 b1 = *(const bf16x8*)&B1[ct * 16 + ll][32 + hl * 8];
      f32x4 a = zero4(); a = MFMA(qa0, b0, a); a = MFMA(qa1, b1, a);
      if (ct == w) {  // causal mask, static indices
#pragma unroll
        for (int r = 0; r < 4; ++r)
          if (ll > hl * 4 + r) a[r] = 0.f;
      }
      aacc[ct] = a;
    } else {
      aacc[ct] = zero4();
    }
  }
  float denA[4];
#pragma unroll
  for (int r = 0; r < 4; ++r)
    denA[r] = aacc[0][r] + aacc[1][r] + aacc[2][r] + aacc[3][r];
#pragma unroll
  for (int m = 1; m <= 8; m <<= 1)
#pragma unroll
    for (int r = 0; r < 4; ++r) denA[r] += __shfl_xor(denA[r], m);
  float inv[4];
#pragma unroll
  for (int r = 0; r < 4; ++r)
    inv[r] = 1.f / (__shfl(den0, hl * 4 + r) + denA[r] + 1e-6f);

  __syncthreads();   // barrier 2: all waves done reading K from B1

  // ---- A transpose -> B1 own stripe -> readback ----
#pragma unroll
  for (int ct = 0; ct < 4; ++ct)
#pragma unroll
    for (int r = 0; r < 4; ++r)
      B1[w * 16 + hl * 4 + r][ct * 16 + ll] = f2bs(aacc[ct][r]);
  const bf16x8 aa0 = *(const bf16x8*)&B1[w * 16 + ll][hl * 8];
  const bf16x8 aa1 = *(const bf16x8*)&B1[w * 16 + ll][32 + hl * 8];

  // ---- num += A V (B2) ----
#pragma unroll
  for (int ct = 0; ct < 4; ++ct) {
    bf16x8 v0 = *(const bf16x8*)&B2[ct * 16 + ll][hl * 8];
    nacc[ct] = MFMA(aa0, v0, nacc[ct]);
    if (w >= 2) {
      bf16x8 v1 = *(const bf16x8*)&B2[ct * 16 + ll][32 + hl * 8];
      nacc[ct] = MFMA(aa1, v1, nacc[ct]);
    }
  }

  // ---- y transpose -> B1 own stripe -> coalesced row-major store ----
#pragma unroll
  for (int ct = 0; ct < 4; ++ct)
#pragma unroll
    for (int r = 0; r < 4; ++r)
      B1[w * 16 + hl * 4 + r][ct * 16 + ll] = f2bs(nacc[ct][r] * inv[r]);
  unsigned short* yb = y + ((size_t)(b * Sv + c * 64)) * 1024 + h * 64;
  {
    int r_ = tid >> 2, c_ = (tid & 3) * 16;   // r_ stays in own wave stripe
    uint4 q0 = *(const uint4*)&B1[r_][c_];
    uint4 q1 = *(const uint4*)&B1[r_][c_ + 8];
    *(uint4*)&yb[(size_t)r_ * 1024 + c_] = q0;
    *(uint4*)&yb[(size_t)r_ * 1024 + c_ + 8] = q1;
  }
}

// ---------------------------------------------------------------------------
// K4: out = y @ Wp. 32 rows/block (2 waves), LDS-free, barrier-free.
// ---------------------------------------------------------------------------
__global__ __launch_bounds__(128) void k_proj(
    const unsigned short* __restrict__ y, const unsigned short* __restrict__ wpT,
    float* __restrict__ out)
{
  const int tid = threadIdx.x, bid = blockIdx.x;
  const int lane = tid & 63, w = tid >> 6;
  const int ll = lane & 15, hl = lane >> 4;
  const size_t row0 = (size_t)bid * 32;

  f32x4 acc[4] = {zero4(), zero4(), zero4(), zero4()};
  const unsigned short* yrow = y + (row0 + w * 16 + ll) * 1024;
#pragma unroll 2
  for (int h = 0; h < 16; ++h) {
    bf16x8 a0 = *(const bf16x8*)(yrow + h * 64 + hl * 8);
    bf16x8 a1 = *(const bf16x8*)(yrow + h * 64 + 32 + hl * 8);
#pragma unroll
    for (int ct = 0; ct < 4; ++ct) {
      const unsigned short* wpr = wpT + (size_t)(ct * 16 + ll) * 1024 + h * 64;
      bf16x8 w0 = *(const bf16x8*)(wpr + hl * 8);
      bf16x8 w1 = *(const bf16x8*)(wpr + 32 + hl * 8);
      acc[ct] = MFMA(a0, w0, acc[ct]);
      acc[ct] = MFMA(a1, w1, acc[ct]);
    }
  }
  float* op = out + (row0 + (size_t)w * 16) * 64;
#pragma unroll
  for (int ct = 0; ct < 4; ++ct)
#pragma unroll
    for (int r = 0; r < 4; ++r)
      op[(size_t)(hl * 4 + r) * 64 + ct * 16 + ll] = acc[ct][r];
}

// ---------------------------------------------------------------------------
extern "C" void kernel_launch(void* const* d_in, const int* in_sizes, int n_in,
                              void* d_out, int out_size, void* d_ws, size_t ws_size,
                              hipStream_t stream)
{
  const float* x  = (const float*)d_in[0];
  const float* Wq = (const float*)d_in[1];
  const float* Wk = (const float*)d_in[2];
  const float* Wv = (const float*)d_in[3];
  const float* Wp = (const float*)d_in[4];
  float* out = (float*)d_out;

  // ws layout: mir bf16 33.55 MB | zmir bf16 0.52 | wqT/wkT/wvT/wpT 0.52 |
  //            y bf16 [16384][1024] 33.55 MB      (total ~68 MB)
  unsigned short* mir = (unsigned short*)d_ws;
  unsigned short* zmir = mir + 16777216;
  unsigned short* wqT = zmir + 262144;
  unsigned short* wkT = wqT + 65536;
  unsigned short* wvT = wkT + 65536;
  unsigned short* wpT = wvT + 65536;
  unsigned short* yb  = wpT + 65536;

  hipLaunchKernelGGL(k_prep_w, dim3(80), dim3(256), 0, stream,
                     Wq, Wk, Wv, Wp, wqT, wkT, wvT, wpT);
  hipLaunchKernelGGL(k_chunk_state, dim3(BHv * NCv), dim3(256), 0, stream,
                     x, wkT, wvT, mir, zmir);
  hipLaunchKernelGGL(k_prefix, dim3(BHv * 17), dim3(256), 0, stream, mir, zmir);
  hipLaunchKernelGGL(k_y, dim3(BHv * NCv), dim3(256), 0, stream,
                     x, wqT, wkT, wvT, mir, zmir, yb);
  hipLaunchKernelGGL(k_proj, dim3((Bv * Sv) / 32), dim3(128), 0, stream,
                     yb, wpT, out);
}

// Round 12
// 162.393 us; speedup vs baseline: 1.0229x; 1.0229x over previous
//
#include <hip/hip_runtime.h>
#include <hip/hip_bf16.h>

// Problem constants
#define Bv 4
#define Sv 4096
#define Dv 1024
#define Hv 16
#define Ov 64
#define NCv 64
#define BHv 64

typedef __attribute__((ext_vector_type(8))) short bf16x8;
typedef __attribute__((ext_vector_type(4))) unsigned short u16x4;
typedef __attribute__((ext_vector_type(8))) unsigned short u16x8;
typedef __attribute__((ext_vector_type(4))) float f32x4;
#define MFMA(a, b, c) __builtin_amdgcn_mfma_f32_16x16x32_bf16(a, b, c, 0, 0, 0)

__device__ __forceinline__ unsigned short f2bs(float f) {
  union { __hip_bfloat16 h; unsigned short u; } v;
  v.h = __float2bfloat16(f);
  return v.u;
}
__device__ __forceinline__ float b2f(unsigned short u) {
  union { unsigned u; float f; } v; v.u = ((unsigned)u) << 16; return v.f;
}
__device__ __forceinline__ float elu1(float a) {
  return a > 0.f ? a + 1.f : __expf(a);
}
__device__ __forceinline__ f32x4 zero4() {
  f32x4 v = {0.f, 0.f, 0.f, 0.f}; return v;
}
__device__ __forceinline__ bf16x8 pack8(float4 a, float4 b) {
  union { u16x8 u; bf16x8 h; } r;
  r.u[0] = f2bs(a.x); r.u[1] = f2bs(a.y); r.u[2] = f2bs(a.z); r.u[3] = f2bs(a.w);
  r.u[4] = f2bs(b.x); r.u[5] = f2bs(b.y); r.u[6] = f2bs(b.z); r.u[7] = f2bs(b.w);
  return r.h;
}

// ---------------------------------------------------------------------------
// K0 prep: Wq/Wk/Wv [h][d][o] -> bf16 [h][o][d]; Wp [d][o2] -> bf16 [o2][d]
// ---------------------------------------------------------------------------
__global__ __launch_bounds__(256) void k_prep_w(
    const float* __restrict__ Wq, const float* __restrict__ Wk,
    const float* __restrict__ Wv, const float* __restrict__ Wp,
    unsigned short* __restrict__ wqT, unsigned short* __restrict__ wkT,
    unsigned short* __restrict__ wvT, unsigned short* __restrict__ wpT)
{
  const int blk = blockIdx.x, tid = threadIdx.x;
  if (blk < 16) {
    int h = blk;
    for (int j = tid; j < 4096; j += 256) {       // j = o*64 + d (output idx)
      int o = j >> 6, d = j & 63;
      int src = h * 4096 + d * 64 + o;
      wqT[h * 4096 + j] = f2bs(Wq[src]);
      wkT[h * 4096 + j] = f2bs(Wk[src]);
      wvT[h * 4096 + j] = f2bs(Wv[src]);
    }
  } else {
    int b2 = blk - 16;
#pragma unroll
    for (int k = 0; k < 4; ++k) {
      int j = b2 * 1024 + tid + k * 256;          // j = o2*1024 + d
      int o = j >> 10, d = j & 1023;
      wpT[j] = f2bs(Wp[d * 64 + o]);
    }
  }
}

// ---------------------------------------------------------------------------
// K1: per (bh,chunk): K=elu1(x Wk), V=x Wv
//   publishes ONLY: mir [o][e] = (K^T V)^T bf16, zmir [e] bf16  (34 MB total)
// ---------------------------------------------------------------------------
__global__ __launch_bounds__(256) void k_chunk_state(
    const float* __restrict__ x, const unsigned short* __restrict__ wkT,
    const unsigned short* __restrict__ wvT, unsigned short* __restrict__ mir,
    unsigned short* __restrict__ zmir)
{
  __shared__ __align__(16) unsigned short kT[64][72];     // K^T[e][t]
  __shared__ __align__(16) unsigned short vT[64][72];     // V^T[o][t]
  __shared__ float zpart[4][64];

  const int tid = threadIdx.x, blk = blockIdx.x;
  const int c = blk & 63, bh = blk >> 6, h = bh & 15, b = bh >> 4;
  const int lane = tid & 63, w = tid >> 6;
  const int ll = lane & 15, hl = lane >> 4;

  const float* xr = x + ((size_t)(b * Sv + c * 64 + w * 16 + ll)) * 1024 + h * 64;
  float4 f0 = *(const float4*)(xr + hl * 8);
  float4 f1 = *(const float4*)(xr + hl * 8 + 4);
  float4 f2 = *(const float4*)(xr + 32 + hl * 8);
  float4 f3 = *(const float4*)(xr + 32 + hl * 8 + 4);
  const bf16x8 xa0 = pack8(f0, f1);
  const bf16x8 xa1 = pack8(f2, f3);

  // K = elu1(x Wk) -> kT + zpart
  const unsigned short* wk = wkT + h * 4096;
#pragma unroll
  for (int ct = 0; ct < 4; ++ct) {
    bf16x8 b0 = *(const bf16x8*)(wk + (ct * 16 + ll) * 64 + hl * 8);
    bf16x8 b1 = *(const bf16x8*)(wk + (ct * 16 + ll) * 64 + 32 + hl * 8);
    f32x4 a = zero4(); a = MFMA(xa0, b0, a); a = MFMA(xa1, b1, a);
    u16x4 p; float part = 0.f;
#pragma unroll
    for (int r = 0; r < 4; ++r) {
      float kv = elu1(a[r]); part += kv;
      p[r] = f2bs(kv);
    }
    *(u16x4*)&kT[ct * 16 + ll][w * 16 + hl * 4] = p;
    part += __shfl_xor(part, 16);
    part += __shfl_xor(part, 32);
    if (hl == 0) zpart[w][ct * 16 + ll] = part;
  }
  // V = x Wv -> vT[o][t]
  const unsigned short* wv = wvT + h * 4096;
#pragma unroll
  for (int ct = 0; ct < 4; ++ct) {
    bf16x8 b0 = *(const bf16x8*)(wv + (ct * 16 + ll) * 64 + hl * 8);
    bf16x8 b1 = *(const bf16x8*)(wv + (ct * 16 + ll) * 64 + 32 + hl * 8);
    f32x4 a = zero4(); a = MFMA(xa0, b0, a); a = MFMA(xa1, b1, a);
    u16x4 p;
#pragma unroll
    for (int r = 0; r < 4; ++r) p[r] = f2bs(a[r]);
    *(u16x4*)&vT[ct * 16 + ll][w * 16 + hl * 4] = p;
  }
  __syncthreads();

  // KtV: C[e][o]; write transposed [o][e] to mir
  const bf16x8 ka0 = *(const bf16x8*)&kT[w * 16 + ll][hl * 8];
  const bf16x8 ka1 = *(const bf16x8*)&kT[w * 16 + ll][32 + hl * 8];
  unsigned short* mp = mir + (size_t)blk * 4096;
#pragma unroll
  for (int ct = 0; ct < 4; ++ct) {
    bf16x8 v0 = *(const bf16x8*)&vT[ct * 16 + ll][hl * 8];
    bf16x8 v1 = *(const bf16x8*)&vT[ct * 16 + ll][32 + hl * 8];
    f32x4 s = zero4(); s = MFMA(ka0, v0, s); s = MFMA(ka1, v1, s);
    u16x4 p;
#pragma unroll
    for (int r = 0; r < 4; ++r) p[r] = f2bs(s[r]);
    *(u16x4*)&mp[(ct * 16 + ll) * 64 + w * 16 + hl * 4] = p;
  }
  if (tid < 64)
    zmir[(size_t)blk * 64 + tid] = f2bs(
        zpart[0][tid] + zpart[1][tid] + zpart[2][tid] + zpart[3][tid]);
}

// ---------------------------------------------------------------------------
// K2: exclusive prefix over chunks — loads up-front, register scan, stores.
// ---------------------------------------------------------------------------
__global__ __launch_bounds__(256) void k_prefix(
    unsigned short* __restrict__ mir, unsigned short* __restrict__ zmir)
{
  const int bh = blockIdx.x / 17, g = blockIdx.x % 17;
  const int tid = threadIdx.x;
  if (g < 16) {
    size_t base = (size_t)bh * 64 * 4096 + g * 256 + tid;
    unsigned short v[64];
#pragma unroll
    for (int cc = 0; cc < 64; ++cc) v[cc] = mir[base + (size_t)cc * 4096];
    float carry = 0.f;
#pragma unroll
    for (int cc = 0; cc < 64; ++cc) {
      float f = b2f(v[cc]);
      v[cc] = f2bs(carry);
      carry += f;
    }
#pragma unroll
    for (int cc = 0; cc < 64; ++cc) mir[base + (size_t)cc * 4096] = v[cc];
  } else if (tid < 64) {
    size_t base = (size_t)bh * 64 * 64 + tid;
    unsigned short v[64];
#pragma unroll
    for (int cc = 0; cc < 64; ++cc) v[cc] = zmir[base + (size_t)cc * 64];
    float carry = 0.f;
#pragma unroll
    for (int cc = 0; cc < 64; ++cc) {
      float f = b2f(v[cc]);
      v[cc] = f2bs(carry);
      carry += f;
    }
#pragma unroll
    for (int cc = 0; cc < 64; ++cc) zmir[base + (size_t)cc * 64] = v[cc];
  }
}

// ---------------------------------------------------------------------------
// K3: per (b,h,chunk) — transposed-compute variant: all LDS staging writes
// are packed b64 (zero scalar ds_write).
//   Q^T = MFMA(WqT-rows, x)  -> packed stage [t][e]
//   K^T = MFMA(WkT-rows, x)  -> packed stage [s][e]
//   A^T = MFMA(K-rows, Q)    -> per-lane denA/inv, packed stage A[t][s]
//   y^T = MFMA(S^T-rows, Q) + MFMA(V^T-rows, A) -> packed stage [t][o]
// B1: Qstage -> K -> (bar2) -> A -> y ; B2: V^T. Two barriers.
// ---------------------------------------------------------------------------
__global__ __launch_bounds__(256) void k_y(
    const float* __restrict__ x, const unsigned short* __restrict__ wqT,
    const unsigned short* __restrict__ wkT, const unsigned short* __restrict__ wvT,
    const unsigned short* __restrict__ mir, const unsigned short* __restrict__ zmir,
    unsigned short* __restrict__ y)
{
  __shared__ __align__(16) unsigned short B1[64][72];  // Q / K / A / y
  __shared__ __align__(16) unsigned short B2[64][72];  // V^T[o][t]

  const int tid = threadIdx.x, blk = blockIdx.x;
  const int c = blk & 63, bh = blk >> 6, h = bh & 15, b = bh >> 4;
  const int lane = tid & 63, w = tid >> 6;
  const int ll = lane & 15, hl = lane >> 4;
  const size_t sblk = (size_t)blk;

  // early independent loads: zprev
  const unsigned short* zp = zmir + sblk * 64;
  u16x8 zz0 = *(const u16x8*)(zp + hl * 8);
  u16x8 zz1 = *(const u16x8*)(zp + 32 + hl * 8);

  // x slice (second read; L3-hot)
  const float* xr = x + ((size_t)(b * Sv + c * 64 + w * 16 + ll)) * 1024 + h * 64;
  float4 f0 = *(const float4*)(xr + hl * 8);
  float4 f1 = *(const float4*)(xr + hl * 8 + 4);
  float4 f2 = *(const float4*)(xr + 32 + hl * 8);
  float4 f3 = *(const float4*)(xr + 32 + hl * 8 + 4);
  const bf16x8 xa0 = pack8(f0, f1);
  const bf16x8 xa1 = pack8(f2, f3);

  // ---- Q^T ladder: D[o][t] = MFMA(WqT-rows, x) -> PACKED stage Q[t][e] ----
  const unsigned short* wq = wqT + h * 4096;
#pragma unroll
  for (int ct = 0; ct < 4; ++ct) {
    bf16x8 a0 = *(const bf16x8*)(wq + (ct * 16 + ll) * 64 + hl * 8);
    bf16x8 a1 = *(const bf16x8*)(wq + (ct * 16 + ll) * 64 + 32 + hl * 8);
    f32x4 a = zero4(); a = MFMA(a0, xa0, a); a = MFMA(a1, xa1, a);
    u16x4 p;
#pragma unroll
    for (int r = 0; r < 4; ++r) p[r] = f2bs(elu1(a[r]));
    *(u16x4*)&B1[w * 16 + ll][ct * 16 + hl * 4] = p;   // Q[t=w16+ll][o..o+3]
  }
  const bf16x8 qa0 = *(const bf16x8*)&B1[w * 16 + ll][hl * 8];
  const bf16x8 qa1 = *(const bf16x8*)&B1[w * 16 + ll][32 + hl * 8];

  // den0 = q . zprev (per-lane, full sum for row t = w*16+ll)
  float den0 = 0.f;
  {
    const u16x8 qu0 = *(const u16x8*)&qa0;
    const u16x8 qu1 = *(const u16x8*)&qa1;
#pragma unroll
    for (int i = 0; i < 8; ++i) {
      den0 += b2f(qu0[i]) * b2f(zz0[i]);
      den0 += b2f(qu1[i]) * b2f(zz1[i]);
    }
    den0 += __shfl_xor(den0, 16);
    den0 += __shfl_xor(den0, 32);
  }

  // ---- K^T ladder -> PACKED stage K[s][e] into B1 own stripe (WAR safe) ----
  const unsigned short* wk = wkT + h * 4096;
#pragma unroll
  for (int ct = 0; ct < 4; ++ct) {
    bf16x8 a0 = *(const bf16x8*)(wk + (ct * 16 + ll) * 64 + hl * 8);
    bf16x8 a1 = *(const bf16x8*)(wk + (ct * 16 + ll) * 64 + 32 + hl * 8);
    f32x4 a = zero4(); a = MFMA(a0, xa0, a); a = MFMA(a1, xa1, a);
    u16x4 p;
#pragma unroll
    for (int r = 0; r < 4; ++r) p[r] = f2bs(elu1(a[r]));
    *(u16x4*)&B1[w * 16 + ll][ct * 16 + hl * 4] = p;   // K[s=w16+ll][e..e+3]
  }
  // ---- V ladder (unswapped) -> B2 as V^T[o][t], packed as before ----
  const unsigned short* wv = wvT + h * 4096;
#pragma unroll
  for (int ct = 0; ct < 4; ++ct) {
    bf16x8 b0 = *(const bf16x8*)(wv + (ct * 16 + ll) * 64 + hl * 8);
    bf16x8 b1 = *(const bf16x8*)(wv + (ct * 16 + ll) * 64 + 32 + hl * 8);
    f32x4 a = zero4(); a = MFMA(xa0, b0, a); a = MFMA(xa1, b1, a);
    u16x4 p;
#pragma unroll
    for (int r = 0; r < 4; ++r) p[r] = f2bs(a[r]);
    *(u16x4*)&B2[ct * 16 + ll][w * 16 + hl * 4] = p;
  }
  __syncthreads();   // barrier 1: K (B1) and V^T (B2) visible to all waves

  // ---- y^T (QS part, mir rows as A-op) interleaved with A^T = K·Q ----
  const unsigned short* sp = mir + sblk * 4096;
  f32x4 nacc[4], aacc[4];
#pragma unroll
  for (int ct = 0; ct < 4; ++ct) {
    bf16x8 s0 = *(const bf16x8*)(sp + (ct * 16 + ll) * 64 + hl * 8);
    bf16x8 s1 = *(const bf16x8*)(sp + (ct * 16 + ll) * 64 + 32 + hl * 8);
    f32x4 n = zero4(); n = MFMA(s0, qa0, n); n = MFMA(s1, qa1, n);
    nacc[ct] = n;                              // y^T[o=ct16+hl4+r][t=w16+ll]
    if (ct <= w) {   // wave-uniform
      bf16x8 k0 = *(const bf16x8*)&B1[ct * 16 + ll][hl * 8];
      bf16x8 k1 = *(const bf16x8*)&B1[ct * 16 + ll][32 + hl * 8];
      f32x4 a = zero4(); a = MFMA(k0, qa0, a); a = MFMA(k1, qa1, a);
      if (ct == w) {  // causal: zero s > t, s = w16+hl4+r, t = w16+ll
#pragma unroll
        for (int r = 0; r < 4; ++r)
          if (hl * 4 + r > ll) a[r] = 0.f;
      }
      aacc[ct] = a;                            // A^T[s=ct16+hl4+r][t=w16+ll]
    } else {
      aacc[ct] = zero4();
    }
  }
  // denA[t]: per-lane partial over its s-values, reduce across hl groups
  float denA = 0.f;
#pragma unroll
  for (int ct = 0; ct < 4; ++ct)
#pragma unroll
    for (int r = 0; r < 4; ++r) denA += aacc[ct][r];
  denA += __shfl_xor(denA, 16);
  denA += __shfl_xor(denA, 32);
  const float inv = 1.f / (den0 + denA + 1e-6f);   // per-lane, row t=w16+ll

  __syncthreads();   // barrier 2: all waves done reading K from B1

  // ---- A stage: PACKED write A[t=w16+ll][s..s+3] ----
#pragma unroll
  for (int ct = 0; ct < 4; ++ct) {
    u16x4 p;
#pragma unroll
    for (int r = 0; r < 4; ++r) p[r] = f2bs(aacc[ct][r]);
    *(u16x4*)&B1[w * 16 + ll][ct * 16 + hl * 4] = p;
  }
  const bf16x8 aa0 = *(const bf16x8*)&B1[w * 16 + ll][hl * 8];
  const bf16x8 aa1 = *(const bf16x8*)&B1[w * 16 + ll][32 + hl * 8];

  // ---- y^T += V^T · A  (vT rows as A-op, aa as B-op) ----
#pragma unroll
  for (int ct = 0; ct < 4; ++ct) {
    bf16x8 v0 = *(const bf16x8*)&B2[ct * 16 + ll][hl * 8];
    nacc[ct] = MFMA(v0, aa0, nacc[ct]);
    if (w >= 2) {    // s in [32,64) nonzero only for t >= 32
      bf16x8 v1 = *(const bf16x8*)&B2[ct * 16 + ll][32 + hl * 8];
      nacc[ct] = MFMA(v1, aa1, nacc[ct]);
    }
  }

  // ---- y stage: PACKED write y[t=w16+ll][o..o+3], then coalesced store ----
#pragma unroll
  for (int ct = 0; ct < 4; ++ct) {
    u16x4 p;
#pragma unroll
    for (int r = 0; r < 4; ++r) p[r] = f2bs(nacc[ct][r] * inv);
    *(u16x4*)&B1[w * 16 + ll][ct * 16 + hl * 4] = p;
  }
  unsigned short* yb = y + ((size_t)(b * Sv + c * 64)) * 1024 + h * 64;
  {
    int r_ = tid >> 2, c_ = (tid & 3) * 16;   // r_ stays in own wave stripe
    uint4 q0 = *(const uint4*)&B1[r_][c_];
    uint4 q1 = *(const uint4*)&B1[r_][c_ + 8];
    *(uint4*)&yb[(size_t)r_ * 1024 + c_] = q0;
    *(uint4*)&yb[(size_t)r_ * 1024 + c_ + 8] = q1;
  }
}

// ---------------------------------------------------------------------------
// K4: out = y @ Wp. 32 rows/block (2 waves), LDS-free, barrier-free.
// ---------------------------------------------------------------------------
__global__ __launch_bounds__(128) void k_proj(
    const unsigned short* __restrict__ y, const unsigned short* __restrict__ wpT,
    float* __restrict__ out)
{
  const int tid = threadIdx.x, bid = blockIdx.x;
  const int lane = tid & 63, w = tid >> 6;
  const int ll = lane & 15, hl = lane >> 4;
  const size_t row0 = (size_t)bid * 32;

  f32x4 acc[4] = {zero4(), zero4(), zero4(), zero4()};
  const unsigned short* yrow = y + (row0 + w * 16 + ll) * 1024;
#pragma unroll 2
  for (int h = 0; h < 16; ++h) {
    bf16x8 a0 = *(const bf16x8*)(yrow + h * 64 + hl * 8);
    bf16x8 a1 = *(const bf16x8*)(yrow + h * 64 + 32 + hl * 8);
#pragma unroll
    for (int ct = 0; ct < 4; ++ct) {
      const unsigned short* wpr = wpT + (size_t)(ct * 16 + ll) * 1024 + h * 64;
      bf16x8 w0 = *(const bf16x8*)(wpr + hl * 8);
      bf16x8 w1 = *(const bf16x8*)(wpr + 32 + hl * 8);
      acc[ct] = MFMA(a0, w0, acc[ct]);
      acc[ct] = MFMA(a1, w1, acc[ct]);
    }
  }
  float* op = out + (row0 + (size_t)w * 16) * 64;
#pragma unroll
  for (int ct = 0; ct < 4; ++ct)
#pragma unroll
    for (int r = 0; r < 4; ++r)
      op[(size_t)(hl * 4 + r) * 64 + ct * 16 + ll] = acc[ct][r];
}

// ---------------------------------------------------------------------------
extern "C" void kernel_launch(void* const* d_in, const int* in_sizes, int n_in,
                              void* d_out, int out_size, void* d_ws, size_t ws_size,
                              hipStream_t stream)
{
  const float* x  = (const float*)d_in[0];
  const float* Wq = (const float*)d_in[1];
  const float* Wk = (const float*)d_in[2];
  const float* Wv = (const float*)d_in[3];
  const float* Wp = (const float*)d_in[4];
  float* out = (float*)d_out;

  // ws layout: mir bf16 33.55 MB | zmir bf16 0.52 | wqT/wkT/wvT/wpT 0.52 |
  //            y bf16 [16384][1024] 33.55 MB      (total ~68 MB)
  unsigned short* mir = (unsigned short*)d_ws;
  unsigned short* zmir = mir + 16777216;
  unsigned short* wqT = zmir + 262144;
  unsigned short* wkT = wqT + 65536;
  unsigned short* wvT = wkT + 65536;
  unsigned short* wpT = wvT + 65536;
  unsigned short* yb  = wpT + 65536;

  hipLaunchKernelGGL(k_prep_w, dim3(80), dim3(256), 0, stream,
                     Wq, Wk, Wv, Wp, wqT, wkT, wvT, wpT);
  hipLaunchKernelGGL(k_chunk_state, dim3(BHv * NCv), dim3(256), 0, stream,
                     x, wkT, wvT, mir, zmir);
  hipLaunchKernelGGL(k_prefix, dim3(BHv * 17), dim3(256), 0, stream, mir, zmir);
  hipLaunchKernelGGL(k_y, dim3(BHv * NCv), dim3(256), 0, stream,
                     x, wqT, wkT, wvT, mir, zmir, yb);
  hipLaunchKernelGGL(k_proj, dim3((Bv * Sv) / 32), dim3(128), 0, stream,
                     yb, wpT, out);
}

// Round 13
// 141.221 us; speedup vs baseline: 1.1763x; 1.1499x over previous
//
#include <hip/hip_runtime.h>
#include <hip/hip_bf16.h>

// Problem constants
#define Bv 4
#define Sv 4096
#define Dv 1024
#define Hv 16
#define Ov 64
#define NCv 64
#define BHv 64

typedef __attribute__((ext_vector_type(8))) short bf16x8;
typedef __attribute__((ext_vector_type(4))) unsigned short u16x4;
typedef __attribute__((ext_vector_type(8))) unsigned short u16x8;
typedef __attribute__((ext_vector_type(4))) float f32x4;
typedef __attribute__((ext_vector_type(16))) float f32x16;
#define MFMA(a, b, c) __builtin_amdgcn_mfma_f32_16x16x32_bf16(a, b, c, 0, 0, 0)
#define MFMA32(a, b, c) __builtin_amdgcn_mfma_f32_32x32x16_bf16(a, b, c, 0, 0, 0)

__device__ __forceinline__ unsigned short f2bs(float f) {
  union { __hip_bfloat16 h; unsigned short u; } v;
  v.h = __float2bfloat16(f);
  return v.u;
}
__device__ __forceinline__ float b2f(unsigned short u) {
  union { unsigned u; float f; } v; v.u = ((unsigned)u) << 16; return v.f;
}
__device__ __forceinline__ float elu1(float a) {
  return a > 0.f ? a + 1.f : __expf(a);
}
__device__ __forceinline__ f32x4 zero4() {
  f32x4 v = {0.f, 0.f, 0.f, 0.f}; return v;
}
__device__ __forceinline__ f32x16 zero16() {
  f32x16 v;
#pragma unroll
  for (int i = 0; i < 16; ++i) v[i] = 0.f;
  return v;
}
__device__ __forceinline__ bf16x8 pack8(float4 a, float4 b) {
  union { u16x8 u; bf16x8 h; } r;
  r.u[0] = f2bs(a.x); r.u[1] = f2bs(a.y); r.u[2] = f2bs(a.z); r.u[3] = f2bs(a.w);
  r.u[4] = f2bs(b.x); r.u[5] = f2bs(b.y); r.u[6] = f2bs(b.z); r.u[7] = f2bs(b.w);
  return r.h;
}
__device__ __forceinline__ bf16x8 ones8() {
  union { u16x8 u; bf16x8 h; } r;
#pragma unroll
  for (int i = 0; i < 8; ++i) r.u[i] = 0x3F80;   // bf16 1.0
  return r.h;
}

// ---------------------------------------------------------------------------
// K0 prep: Wq/Wk/Wv [h][d][o] -> bf16 [h][o][d]; Wp [d][o2] -> bf16 [o2][d]
// ---------------------------------------------------------------------------
__global__ __launch_bounds__(256) void k_prep_w(
    const float* __restrict__ Wq, const float* __restrict__ Wk,
    const float* __restrict__ Wv, const float* __restrict__ Wp,
    unsigned short* __restrict__ wqT, unsigned short* __restrict__ wkT,
    unsigned short* __restrict__ wvT, unsigned short* __restrict__ wpT)
{
  const int blk = blockIdx.x, tid = threadIdx.x;
  if (blk < 16) {
    int h = blk;
    for (int j = tid; j < 4096; j += 256) {       // j = o*64 + d (output idx)
      int o = j >> 6, d = j & 63;
      int src = h * 4096 + d * 64 + o;
      wqT[h * 4096 + j] = f2bs(Wq[src]);
      wkT[h * 4096 + j] = f2bs(Wk[src]);
      wvT[h * 4096 + j] = f2bs(Wv[src]);
    }
  } else {
    int b2 = blk - 16;
#pragma unroll
    for (int k = 0; k < 4; ++k) {
      int j = b2 * 1024 + tid + k * 256;          // j = o2*1024 + d
      int o = j >> 10, d = j & 1023;
      wpT[j] = f2bs(Wp[d * 64 + o]);
    }
  }
}

// ---------------------------------------------------------------------------
// K1 (32x32 MFMA): per (bh,chunk): K=elu1(x Wk), V=x Wv
//   mir [o][e] = (K^T V)^T bf16 ; zmir [e] = colsum(K) bf16 (via ones-MFMA)
// Wave w -> quadrant (wr=w>>1, wc=w&1). ONE barrier.
// ---------------------------------------------------------------------------
__global__ __launch_bounds__(256) void k_chunk_state(
    const float* __restrict__ x, const unsigned short* __restrict__ wkT,
    const unsigned short* __restrict__ wvT, unsigned short* __restrict__ mir,
    unsigned short* __restrict__ zmir)
{
  __shared__ __align__(16) unsigned short Kt[64][72];   // K^T[e][t] (elu'd)
  __shared__ __align__(16) unsigned short Vt[64][72];   // V^T[o][t]

  const int tid = threadIdx.x, blk = blockIdx.x;
  const int c = blk & 63, bh = blk >> 6, h = bh & 15, b = bh >> 4;
  const int l = tid & 63, w = tid >> 6;
  const int wr = w >> 1, wc = w & 1;
  const int l31 = l & 31, g = l >> 5;

  // x fragments: rows t = wr*32 + l31, k-slices d = j*16 + g*8
  const float* xr = x + ((size_t)(b * Sv + c * 64 + wr * 32 + l31)) * 1024 + h * 64;
  bf16x8 xa[4];
#pragma unroll
  for (int j = 0; j < 4; ++j) {
    float4 u0 = *(const float4*)(xr + j * 16 + g * 8);
    float4 u1 = *(const float4*)(xr + j * 16 + g * 8 + 4);
    xa[j] = pack8(u0, u1);
  }

  // K ladder -> Kt[e][t] (packed by 4 along t)
  {
    const unsigned short* wk = wkT + h * 4096;
    f32x16 acc = zero16();
#pragma unroll
    for (int j = 0; j < 4; ++j) {
      bf16x8 bb = *(const bf16x8*)(wk + (wc * 32 + l31) * 64 + j * 16 + g * 8);
      acc = MFMA32(xa[j], bb, acc);
    }
#pragma unroll
    for (int q4 = 0; q4 < 4; ++q4) {
      u16x4 p;
#pragma unroll
      for (int i = 0; i < 4; ++i) p[i] = f2bs(elu1(acc[q4 * 4 + i]));
      *(u16x4*)&Kt[wc * 32 + l31][wr * 32 + 8 * q4 + 4 * g] = p;
    }
  }
  // V ladder -> Vt[o][t] (packed by 4 along t)
  {
    const unsigned short* wv = wvT + h * 4096;
    f32x16 acc = zero16();
#pragma unroll
    for (int j = 0; j < 4; ++j) {
      bf16x8 bb = *(const bf16x8*)(wv + (wc * 32 + l31) * 64 + j * 16 + g * 8);
      acc = MFMA32(xa[j], bb, acc);
    }
#pragma unroll
    for (int q4 = 0; q4 < 4; ++q4) {
      u16x4 p;
#pragma unroll
      for (int i = 0; i < 4; ++i) p[i] = f2bs(acc[q4 * 4 + i]);
      *(u16x4*)&Vt[wc * 32 + l31][wr * 32 + 8 * q4 + 4 * g] = p;
    }
  }
  __syncthreads();

  // KtV: D[e][o] = sum_t K^T[e][t] V[t][o];  z[e] = ones . K (col-replicated)
  f32x16 sacc = zero16(), zacc = zero16();
  const bf16x8 one = ones8();
#pragma unroll
  for (int j = 0; j < 4; ++j) {
    bf16x8 aK = *(const bf16x8*)&Kt[wr * 32 + l31][j * 16 + g * 8];
    bf16x8 vB = *(const bf16x8*)&Vt[wc * 32 + l31][j * 16 + g * 8];
    sacc = MFMA32(aK, vB, sacc);
    bf16x8 kB = *(const bf16x8*)&Kt[wc * 32 + l31][j * 16 + g * 8];
    zacc = MFMA32(one, kB, zacc);
  }
  // mir[o][e], packed by 4 along e
  unsigned short* mp = mir + (size_t)blk * 4096;
#pragma unroll
  for (int q4 = 0; q4 < 4; ++q4) {
    u16x4 p;
#pragma unroll
    for (int i = 0; i < 4; ++i) p[i] = f2bs(sacc[q4 * 4 + i]);
    *(u16x4*)&mp[(size_t)(wc * 32 + l31) * 64 + wr * 32 + 8 * q4 + 4 * g] = p;
  }
  // z write: waves 0,1 (wr==0), lane group g==0, value replicated over rows
  if (w < 2 && g == 0)
    zmir[(size_t)blk * 64 + wc * 32 + l31] = f2bs(zacc[0]);
}

// ---------------------------------------------------------------------------
// K2: exclusive prefix over chunks — loads up-front, register scan, stores.
// ---------------------------------------------------------------------------
__global__ __launch_bounds__(256) void k_prefix(
    unsigned short* __restrict__ mir, unsigned short* __restrict__ zmir)
{
  const int bh = blockIdx.x / 17, g = blockIdx.x % 17;
  const int tid = threadIdx.x;
  if (g < 16) {
    size_t base = (size_t)bh * 64 * 4096 + g * 256 + tid;
    unsigned short v[64];
#pragma unroll
    for (int cc = 0; cc < 64; ++cc) v[cc] = mir[base + (size_t)cc * 4096];
    float carry = 0.f;
#pragma unroll
    for (int cc = 0; cc < 64; ++cc) {
      float f = b2f(v[cc]);
      v[cc] = f2bs(carry);
      carry += f;
    }
#pragma unroll
    for (int cc = 0; cc < 64; ++cc) mir[base + (size_t)cc * 4096] = v[cc];
  } else if (tid < 64) {
    size_t base = (size_t)bh * 64 * 64 + tid;
    unsigned short v[64];
#pragma unroll
    for (int cc = 0; cc < 64; ++cc) v[cc] = zmir[base + (size_t)cc * 64];
    float carry = 0.f;
#pragma unroll
    for (int cc = 0; cc < 64; ++cc) {
      float f = b2f(v[cc]);
      v[cc] = f2bs(carry);
      carry += f;
    }
#pragma unroll
    for (int cc = 0; cc < 64; ++cc) zmir[base + (size_t)cc * 64] = v[cc];
  }
}

// ---------------------------------------------------------------------------
// K3 (32x32 MFMA): per (b,h,chunk):
//   y = (Q Sprev + tril(Q K^T) V) / (q.zprev + rowsum(A) + eps)
// den computed VIA MFMA (Q.z-splat + A.ones -> column-replicated dacc):
// zero shuffles, zero cross-wave reductions. Wave w -> quadrant (wr,wc).
// Buffers: Qb (Q -> A), Kb (K -> y), Vt. Four barriers.
// ---------------------------------------------------------------------------
__global__ __launch_bounds__(256) void k_y(
    const float* __restrict__ x, const unsigned short* __restrict__ wqT,
    const unsigned short* __restrict__ wkT, const unsigned short* __restrict__ wvT,
    const unsigned short* __restrict__ mir, const unsigned short* __restrict__ zmir,
    unsigned short* __restrict__ y)
{
  __shared__ __align__(16) unsigned short Qb[64][72];   // Q[t][e] -> A[t][s]
  __shared__ __align__(16) unsigned short Kb[64][72];   // K[s][e] -> y[t][o]
  __shared__ __align__(16) unsigned short Vt[64][72];   // V^T[o][t]

  const int tid = threadIdx.x, blk = blockIdx.x;
  const int c = blk & 63, bh = blk >> 6, h = bh & 15, b = bh >> 4;
  const int l = tid & 63, w = tid >> 6;
  const int wr = w >> 1, wc = w & 1;
  const int l31 = l & 31, g = l >> 5;
  const size_t sblk = (size_t)blk;

  // x fragments: rows t = wr*32 + l31
  const float* xr = x + ((size_t)(b * Sv + c * 64 + wr * 32 + l31)) * 1024 + h * 64;
  bf16x8 xa[4];
#pragma unroll
  for (int j = 0; j < 4; ++j) {
    float4 u0 = *(const float4*)(xr + j * 16 + g * 8);
    float4 u1 = *(const float4*)(xr + j * 16 + g * 8 + 4);
    xa[j] = pack8(u0, u1);
  }

  // Q ladder -> Qb[t][e]
  {
    const unsigned short* wq = wqT + h * 4096;
    f32x16 acc = zero16();
#pragma unroll
    for (int j = 0; j < 4; ++j) {
      bf16x8 bb = *(const bf16x8*)(wq + (wc * 32 + l31) * 64 + j * 16 + g * 8);
      acc = MFMA32(xa[j], bb, acc);
    }
#pragma unroll
    for (int r = 0; r < 16; ++r)
      Qb[wr * 32 + (r & 3) + 8 * (r >> 2) + 4 * g][wc * 32 + l31] =
          f2bs(elu1(acc[r]));
  }
  // K ladder -> Kb[s][e]
  {
    const unsigned short* wk = wkT + h * 4096;
    f32x16 acc = zero16();
#pragma unroll
    for (int j = 0; j < 4; ++j) {
      bf16x8 bb = *(const bf16x8*)(wk + (wc * 32 + l31) * 64 + j * 16 + g * 8);
      acc = MFMA32(xa[j], bb, acc);
    }
#pragma unroll
    for (int r = 0; r < 16; ++r)
      Kb[wr * 32 + (r & 3) + 8 * (r >> 2) + 4 * g][wc * 32 + l31] =
          f2bs(elu1(acc[r]));
  }
  // V ladder -> Vt[o][t] (packed by 4 along t)
  {
    const unsigned short* wv = wvT + h * 4096;
    f32x16 acc = zero16();
#pragma unroll
    for (int j = 0; j < 4; ++j) {
      bf16x8 bb = *(const bf16x8*)(wv + (wc * 32 + l31) * 64 + j * 16 + g * 8);
      acc = MFMA32(xa[j], bb, acc);
    }
#pragma unroll
    for (int q4 = 0; q4 < 4; ++q4) {
      u16x4 p;
#pragma unroll
      for (int i = 0; i < 4; ++i) p[i] = f2bs(acc[q4 * 4 + i]);
      *(u16x4*)&Vt[wc * 32 + l31][wr * 32 + 8 * q4 + 4 * g] = p;
    }
  }
  __syncthreads();   // bar1: Q,K,V^T staged

  // Q fragments (rows t = wr*32 + l31, full e)
  bf16x8 qa[4];
#pragma unroll
  for (int j = 0; j < 4; ++j)
    qa[j] = *(const bf16x8*)&Qb[wr * 32 + l31][j * 16 + g * 8];
  // z splat fragments (independent of lane column)
  const unsigned short* zp = zmir + sblk * 64;
  bf16x8 zf[4];
#pragma unroll
  for (int j = 0; j < 4; ++j)
    zf[j] = *(const bf16x8*)(zp + j * 16 + g * 8);

  // A = tril(Q K^T), nacc = Q Sprev, dacc = Q.z (col-replicated)
  const unsigned short* sp = mir + sblk * 4096;
  f32x16 aacc = zero16(), nacc = zero16(), dacc = zero16();
#pragma unroll
  for (int j = 0; j < 4; ++j) {
    bf16x8 sB = *(const bf16x8*)(sp + (size_t)(wc * 32 + l31) * 64 + j * 16 + g * 8);
    nacc = MFMA32(qa[j], sB, nacc);
    dacc = MFMA32(qa[j], zf[j], dacc);
  }
  if (w != 1) {  // wave 1 (wr=0,wc=1) is strictly upper -> A quadrant = 0
#pragma unroll
    for (int j = 0; j < 4; ++j) {
      bf16x8 kB = *(const bf16x8*)&Kb[wc * 32 + l31][j * 16 + g * 8];
      aacc = MFMA32(qa[j], kB, aacc);
    }
    if (w == 0 || w == 3) {  // diagonal quadrants: zero s > t
#pragma unroll
      for (int r = 0; r < 16; ++r)
        if (l31 > (r & 3) + 8 * (r >> 2) + 4 * g) aacc[r] = 0.f;
    }
  }
  __syncthreads();   // bar2: all waves done reading Qb (Q) and Kb (K)

  // stage A[t][s] into Qb
#pragma unroll
  for (int r = 0; r < 16; ++r)
    Qb[wr * 32 + (r & 3) + 8 * (r >> 2) + 4 * g][wc * 32 + l31] = f2bs(aacc[r]);
  __syncthreads();   // bar3: A staged

  // nacc += A V ; dacc += A . ones (rowsum, col-replicated)
  const bf16x8 one = ones8();
#pragma unroll
  for (int j = 0; j < 4; ++j) {
    bf16x8 aA = *(const bf16x8*)&Qb[wr * 32 + l31][j * 16 + g * 8];
    bf16x8 vB = *(const bf16x8*)&Vt[wc * 32 + l31][j * 16 + g * 8];
    nacc = MFMA32(aA, vB, nacc);
    dacc = MFMA32(aA, one, dacc);
  }

  // y = nacc / (dacc + eps) -> stage into Kb[t][o]
#pragma unroll
  for (int r = 0; r < 16; ++r)
    Kb[wr * 32 + (r & 3) + 8 * (r >> 2) + 4 * g][wc * 32 + l31] =
        f2bs(nacc[r] / (dacc[r] + 1e-6f));
  __syncthreads();   // bar4: y staged

  // coalesced row-major y store
  unsigned short* yb = y + ((size_t)(b * Sv + c * 64)) * 1024 + h * 64;
  {
    int r_ = tid >> 2, c_ = (tid & 3) * 16;
    uint4 q0 = *(const uint4*)&Kb[r_][c_];
    uint4 q1 = *(const uint4*)&Kb[r_][c_ + 8];
    *(uint4*)&yb[(size_t)r_ * 1024 + c_] = q0;
    *(uint4*)&yb[(size_t)r_ * 1024 + c_ + 8] = q1;
  }
}

// ---------------------------------------------------------------------------
// K4: out = y @ Wp. 32 rows/block (2 waves), LDS-free, barrier-free.
// ---------------------------------------------------------------------------
__global__ __launch_bounds__(128) void k_proj(
    const unsigned short* __restrict__ y, const unsigned short* __restrict__ wpT,
    float* __restrict__ out)
{
  const int tid = threadIdx.x, bid = blockIdx.x;
  const int lane = tid & 63, w = tid >> 6;
  const int ll = lane & 15, hl = lane >> 4;
  const size_t row0 = (size_t)bid * 32;

  f32x4 acc[4] = {zero4(), zero4(), zero4(), zero4()};
  const unsigned short* yrow = y + (row0 + w * 16 + ll) * 1024;
#pragma unroll 2
  for (int h = 0; h < 16; ++h) {
    bf16x8 a0 = *(const bf16x8*)(yrow + h * 64 + hl * 8);
    bf16x8 a1 = *(const bf16x8*)(yrow + h * 64 + 32 + hl * 8);
#pragma unroll
    for (int ct = 0; ct < 4; ++ct) {
      const unsigned short* wpr = wpT + (size_t)(ct * 16 + ll) * 1024 + h * 64;
      bf16x8 w0 = *(const bf16x8*)(wpr + hl * 8);
      bf16x8 w1 = *(const bf16x8*)(wpr + 32 + hl * 8);
      acc[ct] = MFMA(a0, w0, acc[ct]);
      acc[ct] = MFMA(a1, w1, acc[ct]);
    }
  }
  float* op = out + (row0 + (size_t)w * 16) * 64;
#pragma unroll
  for (int ct = 0; ct < 4; ++ct)
#pragma unroll
    for (int r = 0; r < 4; ++r)
      op[(size_t)(hl * 4 + r) * 64 + ct * 16 + ll] = acc[ct][r];
}

// ---------------------------------------------------------------------------
extern "C" void kernel_launch(void* const* d_in, const int* in_sizes, int n_in,
                              void* d_out, int out_size, void* d_ws, size_t ws_size,
                              hipStream_t stream)
{
  const float* x  = (const float*)d_in[0];
  const float* Wq = (const float*)d_in[1];
  const float* Wk = (const float*)d_in[2];
  const float* Wv = (const float*)d_in[3];
  const float* Wp = (const float*)d_in[4];
  float* out = (float*)d_out;

  // ws layout: mir bf16 33.55 MB | zmir bf16 0.52 | wqT/wkT/wvT/wpT 0.52 |
  //            y bf16 [16384][1024] 33.55 MB      (total ~68 MB)
  unsigned short* mir = (unsigned short*)d_ws;
  unsigned short* zmir = mir + 16777216;
  unsigned short* wqT = zmir + 262144;
  unsigned short* wkT = wqT + 65536;
  unsigned short* wvT = wkT + 65536;
  unsigned short* wpT = wvT + 65536;
  unsigned short* yb  = wpT + 65536;

  hipLaunchKernelGGL(k_prep_w, dim3(80), dim3(256), 0, stream,
                     Wq, Wk, Wv, Wp, wqT, wkT, wvT, wpT);
  hipLaunchKernelGGL(k_chunk_state, dim3(BHv * NCv), dim3(256), 0, stream,
                     x, wkT, wvT, mir, zmir);
  hipLaunchKernelGGL(k_prefix, dim3(BHv * 17), dim3(256), 0, stream, mir, zmir);
  hipLaunchKernelGGL(k_y, dim3(BHv * NCv), dim3(256), 0, stream,
                     x, wqT, wkT, wvT, mir, zmir, yb);
  hipLaunchKernelGGL(k_proj, dim3((Bv * Sv) / 32), dim3(128), 0, stream,
                     yb, wpT, out);
}

// Round 14
// 136.161 us; speedup vs baseline: 1.2200x; 1.0372x over previous
//
#include <hip/hip_runtime.h>
#include <hip/hip_bf16.h>

// Problem constants
#define Bv 4
#define Sv 4096
#define Dv 1024
#define Hv 16
#define Ov 64
#define NCv 64
#define BHv 64

typedef __attribute__((ext_vector_type(8))) short bf16x8;
typedef __attribute__((ext_vector_type(4))) unsigned short u16x4;
typedef __attribute__((ext_vector_type(8))) unsigned short u16x8;
typedef __attribute__((ext_vector_type(4))) float f32x4;
typedef __attribute__((ext_vector_type(16))) float f32x16;
#define MFMA(a, b, c) __builtin_amdgcn_mfma_f32_16x16x32_bf16(a, b, c, 0, 0, 0)
#define MFMA32(a, b, c) __builtin_amdgcn_mfma_f32_32x32x16_bf16(a, b, c, 0, 0, 0)

__device__ __forceinline__ unsigned short f2bs(float f) {
  union { __hip_bfloat16 h; unsigned short u; } v;
  v.h = __float2bfloat16(f);
  return v.u;
}
__device__ __forceinline__ float b2f(unsigned short u) {
  union { unsigned u; float f; } v; v.u = ((unsigned)u) << 16; return v.f;
}
__device__ __forceinline__ float elu1(float a) {
  return a > 0.f ? a + 1.f : __expf(a);
}
__device__ __forceinline__ f32x4 zero4() {
  f32x4 v = {0.f, 0.f, 0.f, 0.f}; return v;
}
__device__ __forceinline__ f32x16 zero16() {
  f32x16 v;
#pragma unroll
  for (int i = 0; i < 16; ++i) v[i] = 0.f;
  return v;
}
__device__ __forceinline__ bf16x8 pack8(float4 a, float4 b) {
  union { u16x8 u; bf16x8 h; } r;
  r.u[0] = f2bs(a.x); r.u[1] = f2bs(a.y); r.u[2] = f2bs(a.z); r.u[3] = f2bs(a.w);
  r.u[4] = f2bs(b.x); r.u[5] = f2bs(b.y); r.u[6] = f2bs(b.z); r.u[7] = f2bs(b.w);
  return r.h;
}
__device__ __forceinline__ bf16x8 ones8() {
  union { u16x8 u; bf16x8 h; } r;
#pragma unroll
  for (int i = 0; i < 8; ++i) r.u[i] = 0x3F80;   // bf16 1.0
  return r.h;
}

// ---------------------------------------------------------------------------
// K0 prep: Wq/Wk/Wv [h][d][o] -> bf16 [h][o][d]; Wp [d][o2] -> bf16 [o2][d]
// ---------------------------------------------------------------------------
__global__ __launch_bounds__(256) void k_prep_w(
    const float* __restrict__ Wq, const float* __restrict__ Wk,
    const float* __restrict__ Wv, const float* __restrict__ Wp,
    unsigned short* __restrict__ wqT, unsigned short* __restrict__ wkT,
    unsigned short* __restrict__ wvT, unsigned short* __restrict__ wpT)
{
  const int blk = blockIdx.x, tid = threadIdx.x;
  if (blk < 16) {
    int h = blk;
    for (int j = tid; j < 4096; j += 256) {       // j = o*64 + d (output idx)
      int o = j >> 6, d = j & 63;
      int src = h * 4096 + d * 64 + o;
      wqT[h * 4096 + j] = f2bs(Wq[src]);
      wkT[h * 4096 + j] = f2bs(Wk[src]);
      wvT[h * 4096 + j] = f2bs(Wv[src]);
    }
  } else {
    int b2 = blk - 16;
#pragma unroll
    for (int k = 0; k < 4; ++k) {
      int j = b2 * 1024 + tid + k * 256;          // j = o2*1024 + d
      int o = j >> 10, d = j & 1023;
      wpT[j] = f2bs(Wp[d * 64 + o]);
    }
  }
}

// ---------------------------------------------------------------------------
// K1 (32x32 MFMA): per (bh,chunk): K=elu1(x Wk), V=x Wv
//   mir [o][e] = (K^T V)^T bf16 ; zmir [e] = colsum(K) bf16 (via ones-MFMA)
// Wave w -> quadrant (wr=w>>1, wc=w&1). ONE barrier.
// ---------------------------------------------------------------------------
__global__ __launch_bounds__(256) void k_chunk_state(
    const float* __restrict__ x, const unsigned short* __restrict__ wkT,
    const unsigned short* __restrict__ wvT, unsigned short* __restrict__ mir,
    unsigned short* __restrict__ zmir)
{
  __shared__ __align__(16) unsigned short Kt[64][72];   // K^T[e][t] (elu'd)
  __shared__ __align__(16) unsigned short Vt[64][72];   // V^T[o][t]

  const int tid = threadIdx.x, blk = blockIdx.x;
  const int c = blk & 63, bh = blk >> 6, h = bh & 15, b = bh >> 4;
  const int l = tid & 63, w = tid >> 6;
  const int wr = w >> 1, wc = w & 1;
  const int l31 = l & 31, g = l >> 5;

  // x fragments: rows t = wr*32 + l31, k-slices d = j*16 + g*8
  const float* xr = x + ((size_t)(b * Sv + c * 64 + wr * 32 + l31)) * 1024 + h * 64;
  bf16x8 xa[4];
#pragma unroll
  for (int j = 0; j < 4; ++j) {
    float4 u0 = *(const float4*)(xr + j * 16 + g * 8);
    float4 u1 = *(const float4*)(xr + j * 16 + g * 8 + 4);
    xa[j] = pack8(u0, u1);
  }

  // K ladder -> Kt[e][t] (packed by 4 along t)
  {
    const unsigned short* wk = wkT + h * 4096;
    f32x16 acc = zero16();
#pragma unroll
    for (int j = 0; j < 4; ++j) {
      bf16x8 bb = *(const bf16x8*)(wk + (wc * 32 + l31) * 64 + j * 16 + g * 8);
      acc = MFMA32(xa[j], bb, acc);
    }
#pragma unroll
    for (int q4 = 0; q4 < 4; ++q4) {
      u16x4 p;
#pragma unroll
      for (int i = 0; i < 4; ++i) p[i] = f2bs(elu1(acc[q4 * 4 + i]));
      *(u16x4*)&Kt[wc * 32 + l31][wr * 32 + 8 * q4 + 4 * g] = p;
    }
  }
  // V ladder -> Vt[o][t] (packed by 4 along t)
  {
    const unsigned short* wv = wvT + h * 4096;
    f32x16 acc = zero16();
#pragma unroll
    for (int j = 0; j < 4; ++j) {
      bf16x8 bb = *(const bf16x8*)(wv + (wc * 32 + l31) * 64 + j * 16 + g * 8);
      acc = MFMA32(xa[j], bb, acc);
    }
#pragma unroll
    for (int q4 = 0; q4 < 4; ++q4) {
      u16x4 p;
#pragma unroll
      for (int i = 0; i < 4; ++i) p[i] = f2bs(acc[q4 * 4 + i]);
      *(u16x4*)&Vt[wc * 32 + l31][wr * 32 + 8 * q4 + 4 * g] = p;
    }
  }
  __syncthreads();

  // KtV: D[e][o] = sum_t K^T[e][t] V[t][o];  z[e] = ones . K (col-replicated)
  f32x16 sacc = zero16(), zacc = zero16();
  const bf16x8 one = ones8();
#pragma unroll
  for (int j = 0; j < 4; ++j) {
    bf16x8 aK = *(const bf16x8*)&Kt[wr * 32 + l31][j * 16 + g * 8];
    bf16x8 vB = *(const bf16x8*)&Vt[wc * 32 + l31][j * 16 + g * 8];
    sacc = MFMA32(aK, vB, sacc);
    bf16x8 kB = *(const bf16x8*)&Kt[wc * 32 + l31][j * 16 + g * 8];
    zacc = MFMA32(one, kB, zacc);
  }
  // mir[o][e], packed by 4 along e
  unsigned short* mp = mir + (size_t)blk * 4096;
#pragma unroll
  for (int q4 = 0; q4 < 4; ++q4) {
    u16x4 p;
#pragma unroll
    for (int i = 0; i < 4; ++i) p[i] = f2bs(sacc[q4 * 4 + i]);
    *(u16x4*)&mp[(size_t)(wc * 32 + l31) * 64 + wr * 32 + 8 * q4 + 4 * g] = p;
  }
  // z write: waves 0,1 (wr==0), lane group g==0, value replicated over rows
  if (w < 2 && g == 0)
    zmir[(size_t)blk * 64 + wc * 32 + l31] = f2bs(zacc[0]);
}

// ---------------------------------------------------------------------------
// K2: exclusive prefix over chunks — loads up-front, register scan, stores.
// ---------------------------------------------------------------------------
__global__ __launch_bounds__(256) void k_prefix(
    unsigned short* __restrict__ mir, unsigned short* __restrict__ zmir)
{
  const int bh = blockIdx.x / 17, g = blockIdx.x % 17;
  const int tid = threadIdx.x;
  if (g < 16) {
    size_t base = (size_t)bh * 64 * 4096 + g * 256 + tid;
    unsigned short v[64];
#pragma unroll
    for (int cc = 0; cc < 64; ++cc) v[cc] = mir[base + (size_t)cc * 4096];
    float carry = 0.f;
#pragma unroll
    for (int cc = 0; cc < 64; ++cc) {
      float f = b2f(v[cc]);
      v[cc] = f2bs(carry);
      carry += f;
    }
#pragma unroll
    for (int cc = 0; cc < 64; ++cc) mir[base + (size_t)cc * 4096] = v[cc];
  } else if (tid < 64) {
    size_t base = (size_t)bh * 64 * 64 + tid;
    unsigned short v[64];
#pragma unroll
    for (int cc = 0; cc < 64; ++cc) v[cc] = zmir[base + (size_t)cc * 64];
    float carry = 0.f;
#pragma unroll
    for (int cc = 0; cc < 64; ++cc) {
      float f = b2f(v[cc]);
      v[cc] = f2bs(carry);
      carry += f;
    }
#pragma unroll
    for (int cc = 0; cc < 64; ++cc) zmir[base + (size_t)cc * 64] = v[cc];
  }
}

// ---------------------------------------------------------------------------
// K3 (32x32 MFMA): per (b,h,chunk):
//   y = (Q Sprev + tril(Q K^T) V) / (q.zprev + rowsum(A) + eps)
// den via MFMA (Q.z-splat + A.ones -> column-replicated dacc); zero shuffles.
// Division via v_rcp_f32 (rcp error << bf16 quantization).
// ---------------------------------------------------------------------------
__global__ __launch_bounds__(256) void k_y(
    const float* __restrict__ x, const unsigned short* __restrict__ wqT,
    const unsigned short* __restrict__ wkT, const unsigned short* __restrict__ wvT,
    const unsigned short* __restrict__ mir, const unsigned short* __restrict__ zmir,
    unsigned short* __restrict__ y)
{
  __shared__ __align__(16) unsigned short Qb[64][72];   // Q[t][e] -> A[t][s]
  __shared__ __align__(16) unsigned short Kb[64][72];   // K[s][e] -> y[t][o]
  __shared__ __align__(16) unsigned short Vt[64][72];   // V^T[o][t]

  const int tid = threadIdx.x, blk = blockIdx.x;
  const int c = blk & 63, bh = blk >> 6, h = bh & 15, b = bh >> 4;
  const int l = tid & 63, w = tid >> 6;
  const int wr = w >> 1, wc = w & 1;
  const int l31 = l & 31, g = l >> 5;
  const size_t sblk = (size_t)blk;

  // x fragments: rows t = wr*32 + l31
  const float* xr = x + ((size_t)(b * Sv + c * 64 + wr * 32 + l31)) * 1024 + h * 64;
  bf16x8 xa[4];
#pragma unroll
  for (int j = 0; j < 4; ++j) {
    float4 u0 = *(const float4*)(xr + j * 16 + g * 8);
    float4 u1 = *(const float4*)(xr + j * 16 + g * 8 + 4);
    xa[j] = pack8(u0, u1);
  }

  // Q ladder -> Qb[t][e]
  {
    const unsigned short* wq = wqT + h * 4096;
    f32x16 acc = zero16();
#pragma unroll
    for (int j = 0; j < 4; ++j) {
      bf16x8 bb = *(const bf16x8*)(wq + (wc * 32 + l31) * 64 + j * 16 + g * 8);
      acc = MFMA32(xa[j], bb, acc);
    }
#pragma unroll
    for (int r = 0; r < 16; ++r)
      Qb[wr * 32 + (r & 3) + 8 * (r >> 2) + 4 * g][wc * 32 + l31] =
          f2bs(elu1(acc[r]));
  }
  // K ladder -> Kb[s][e]
  {
    const unsigned short* wk = wkT + h * 4096;
    f32x16 acc = zero16();
#pragma unroll
    for (int j = 0; j < 4; ++j) {
      bf16x8 bb = *(const bf16x8*)(wk + (wc * 32 + l31) * 64 + j * 16 + g * 8);
      acc = MFMA32(xa[j], bb, acc);
    }
#pragma unroll
    for (int r = 0; r < 16; ++r)
      Kb[wr * 32 + (r & 3) + 8 * (r >> 2) + 4 * g][wc * 32 + l31] =
          f2bs(elu1(acc[r]));
  }
  // V ladder -> Vt[o][t] (packed by 4 along t)
  {
    const unsigned short* wv = wvT + h * 4096;
    f32x16 acc = zero16();
#pragma unroll
    for (int j = 0; j < 4; ++j) {
      bf16x8 bb = *(const bf16x8*)(wv + (wc * 32 + l31) * 64 + j * 16 + g * 8);
      acc = MFMA32(xa[j], bb, acc);
    }
#pragma unroll
    for (int q4 = 0; q4 < 4; ++q4) {
      u16x4 p;
#pragma unroll
      for (int i = 0; i < 4; ++i) p[i] = f2bs(acc[q4 * 4 + i]);
      *(u16x4*)&Vt[wc * 32 + l31][wr * 32 + 8 * q4 + 4 * g] = p;
    }
  }
  __syncthreads();   // bar1: Q,K,V^T staged

  // Q fragments (rows t = wr*32 + l31, full e)
  bf16x8 qa[4];
#pragma unroll
  for (int j = 0; j < 4; ++j)
    qa[j] = *(const bf16x8*)&Qb[wr * 32 + l31][j * 16 + g * 8];
  // z splat fragments (independent of lane column)
  const unsigned short* zp = zmir + sblk * 64;
  bf16x8 zf[4];
#pragma unroll
  for (int j = 0; j < 4; ++j)
    zf[j] = *(const bf16x8*)(zp + j * 16 + g * 8);

  // A = tril(Q K^T), nacc = Q Sprev, dacc = Q.z (col-replicated)
  const unsigned short* sp = mir + sblk * 4096;
  f32x16 aacc = zero16(), nacc = zero16(), dacc = zero16();
#pragma unroll
  for (int j = 0; j < 4; ++j) {
    bf16x8 sB = *(const bf16x8*)(sp + (size_t)(wc * 32 + l31) * 64 + j * 16 + g * 8);
    nacc = MFMA32(qa[j], sB, nacc);
    dacc = MFMA32(qa[j], zf[j], dacc);
  }
  if (w != 1) {  // wave 1 (wr=0,wc=1) is strictly upper -> A quadrant = 0
#pragma unroll
    for (int j = 0; j < 4; ++j) {
      bf16x8 kB = *(const bf16x8*)&Kb[wc * 32 + l31][j * 16 + g * 8];
      aacc = MFMA32(qa[j], kB, aacc);
    }
    if (w == 0 || w == 3) {  // diagonal quadrants: zero s > t
#pragma unroll
      for (int r = 0; r < 16; ++r)
        if (l31 > (r & 3) + 8 * (r >> 2) + 4 * g) aacc[r] = 0.f;
    }
  }
  __syncthreads();   // bar2: all waves done reading Qb (Q) and Kb (K)

  // stage A[t][s] into Qb
#pragma unroll
  for (int r = 0; r < 16; ++r)
    Qb[wr * 32 + (r & 3) + 8 * (r >> 2) + 4 * g][wc * 32 + l31] = f2bs(aacc[r]);
  __syncthreads();   // bar3: A staged

  // nacc += A V ; dacc += A . ones (rowsum, col-replicated)
  const bf16x8 one = ones8();
#pragma unroll
  for (int j = 0; j < 4; ++j) {
    bf16x8 aA = *(const bf16x8*)&Qb[wr * 32 + l31][j * 16 + g * 8];
    bf16x8 vB = *(const bf16x8*)&Vt[wc * 32 + l31][j * 16 + g * 8];
    nacc = MFMA32(aA, vB, nacc);
    dacc = MFMA32(aA, one, dacc);
  }

  // y = nacc * rcp(dacc + eps) -> stage into Kb[t][o]
#pragma unroll
  for (int r = 0; r < 16; ++r) {
    float invd = __builtin_amdgcn_rcpf(dacc[r] + 1e-6f);
    Kb[wr * 32 + (r & 3) + 8 * (r >> 2) + 4 * g][wc * 32 + l31] =
        f2bs(nacc[r] * invd);
  }
  __syncthreads();   // bar4: y staged

  // coalesced row-major y store
  unsigned short* yb = y + ((size_t)(b * Sv + c * 64)) * 1024 + h * 64;
  {
    int r_ = tid >> 2, c_ = (tid & 3) * 16;
    uint4 q0 = *(const uint4*)&Kb[r_][c_];
    uint4 q1 = *(const uint4*)&Kb[r_][c_ + 8];
    *(uint4*)&yb[(size_t)r_ * 1024 + c_] = q0;
    *(uint4*)&yb[(size_t)r_ * 1024 + c_ + 8] = q1;
  }
}

// ---------------------------------------------------------------------------
// K4 (32x32 MFMA): out = y @ Wp. 64 rows/block, 4 waves = quadrants,
// K=1024 as two independent accumulator chains (even/odd k-steps).
// LDS-free, barrier-free.
// ---------------------------------------------------------------------------
__global__ __launch_bounds__(256) void k_proj(
    const unsigned short* __restrict__ y, const unsigned short* __restrict__ wpT,
    float* __restrict__ out)
{
  const int tid = threadIdx.x, bid = blockIdx.x;
  const int l = tid & 63, w = tid >> 6;
  const int wr = w >> 1, wc = w & 1;
  const int l31 = l & 31, g = l >> 5;
  const size_t row0 = (size_t)bid * 64;

  const unsigned short* yrow = y + (row0 + wr * 32 + l31) * 1024 + g * 8;
  const unsigned short* wpr = wpT + (size_t)(wc * 32 + l31) * 1024 + g * 8;

  f32x16 acc0 = zero16(), acc1 = zero16();
#pragma unroll 4
  for (int jj = 0; jj < 64; jj += 2) {
    bf16x8 a0 = *(const bf16x8*)(yrow + jj * 16);
    bf16x8 b0 = *(const bf16x8*)(wpr + jj * 16);
    acc0 = MFMA32(a0, b0, acc0);
    bf16x8 a1 = *(const bf16x8*)(yrow + jj * 16 + 16);
    bf16x8 b1 = *(const bf16x8*)(wpr + jj * 16 + 16);
    acc1 = MFMA32(a1, b1, acc1);
  }
  float* op = out + (row0 + wr * 32) * 64 + wc * 32;
#pragma unroll
  for (int r = 0; r < 16; ++r)
    op[(size_t)((r & 3) + 8 * (r >> 2) + 4 * g) * 64 + l31] = acc0[r] + acc1[r];
}

// ---------------------------------------------------------------------------
extern "C" void kernel_launch(void* const* d_in, const int* in_sizes, int n_in,
                              void* d_out, int out_size, void* d_ws, size_t ws_size,
                              hipStream_t stream)
{
  const float* x  = (const float*)d_in[0];
  const float* Wq = (const float*)d_in[1];
  const float* Wk = (const float*)d_in[2];
  const float* Wv = (const float*)d_in[3];
  const float* Wp = (const float*)d_in[4];
  float* out = (float*)d_out;

  // ws layout: mir bf16 33.55 MB | zmir bf16 0.52 | wqT/wkT/wvT/wpT 0.52 |
  //            y bf16 [16384][1024] 33.55 MB      (total ~68 MB)
  unsigned short* mir = (unsigned short*)d_ws;
  unsigned short* zmir = mir + 16777216;
  unsigned short* wqT = zmir + 262144;
  unsigned short* wkT = wqT + 65536;
  unsigned short* wvT = wkT + 65536;
  unsigned short* wpT = wvT + 65536;
  unsigned short* yb  = wpT + 65536;

  hipLaunchKernelGGL(k_prep_w, dim3(80), dim3(256), 0, stream,
                     Wq, Wk, Wv, Wp, wqT, wkT, wvT, wpT);
  hipLaunchKernelGGL(k_chunk_state, dim3(BHv * NCv), dim3(256), 0, stream,
                     x, wkT, wvT, mir, zmir);
  hipLaunchKernelGGL(k_prefix, dim3(BHv * 17), dim3(256), 0, stream, mir, zmir);
  hipLaunchKernelGGL(k_y, dim3(BHv * NCv), dim3(256), 0, stream,
                     x, wqT, wkT, wvT, mir, zmir, yb);
  hipLaunchKernelGGL(k_proj, dim3((Bv * Sv) / 64), dim3(256), 0, stream,
                     yb, wpT, out);
}

// Round 15
// 135.651 us; speedup vs baseline: 1.2246x; 1.0038x over previous
//
#include <hip/hip_runtime.h>
#include <hip/hip_bf16.h>

// Problem constants
#define Bv 4
#define Sv 4096
#define Dv 1024
#define Hv 16
#define Ov 64
#define NCv 64
#define BHv 64

typedef __attribute__((ext_vector_type(8))) short bf16x8;
typedef __attribute__((ext_vector_type(4))) unsigned short u16x4;
typedef __attribute__((ext_vector_type(8))) unsigned short u16x8;
typedef __attribute__((ext_vector_type(4))) float f32x4;
typedef __attribute__((ext_vector_type(16))) float f32x16;
#define MFMA(a, b, c) __builtin_amdgcn_mfma_f32_16x16x32_bf16(a, b, c, 0, 0, 0)
#define MFMA32(a, b, c) __builtin_amdgcn_mfma_f32_32x32x16_bf16(a, b, c, 0, 0, 0)

__device__ __forceinline__ unsigned short f2bs(float f) {
  union { __hip_bfloat16 h; unsigned short u; } v;
  v.h = __float2bfloat16(f);
  return v.u;
}
__device__ __forceinline__ float b2f(unsigned short u) {
  union { unsigned u; float f; } v; v.u = ((unsigned)u) << 16; return v.f;
}
__device__ __forceinline__ float elu1(float a) {
  return a > 0.f ? a + 1.f : __expf(a);
}
__device__ __forceinline__ f32x4 zero4() {
  f32x4 v = {0.f, 0.f, 0.f, 0.f}; return v;
}
__device__ __forceinline__ f32x16 zero16() {
  f32x16 v;
#pragma unroll
  for (int i = 0; i < 16; ++i) v[i] = 0.f;
  return v;
}
__device__ __forceinline__ bf16x8 pack8(float4 a, float4 b) {
  union { u16x8 u; bf16x8 h; } r;
  r.u[0] = f2bs(a.x); r.u[1] = f2bs(a.y); r.u[2] = f2bs(a.z); r.u[3] = f2bs(a.w);
  r.u[4] = f2bs(b.x); r.u[5] = f2bs(b.y); r.u[6] = f2bs(b.z); r.u[7] = f2bs(b.w);
  return r.h;
}
__device__ __forceinline__ bf16x8 ones8() {
  union { u16x8 u; bf16x8 h; } r;
#pragma unroll
  for (int i = 0; i < 8; ++i) r.u[i] = 0x3F80;   // bf16 1.0
  return r.h;
}

// ---------------------------------------------------------------------------
// K0 prep: Wq/Wk/Wv [h][d][o] -> bf16 [h][o][d]; Wp [d][o2] -> bf16 [o2][d]
// ---------------------------------------------------------------------------
__global__ __launch_bounds__(256) void k_prep_w(
    const float* __restrict__ Wq, const float* __restrict__ Wk,
    const float* __restrict__ Wv, const float* __restrict__ Wp,
    unsigned short* __restrict__ wqT, unsigned short* __restrict__ wkT,
    unsigned short* __restrict__ wvT, unsigned short* __restrict__ wpT)
{
  const int blk = blockIdx.x, tid = threadIdx.x;
  if (blk < 16) {
    int h = blk;
    for (int j = tid; j < 4096; j += 256) {       // j = o*64 + d (output idx)
      int o = j >> 6, d = j & 63;
      int src = h * 4096 + d * 64 + o;
      wqT[h * 4096 + j] = f2bs(Wq[src]);
      wkT[h * 4096 + j] = f2bs(Wk[src]);
      wvT[h * 4096 + j] = f2bs(Wv[src]);
    }
  } else {
    int b2 = blk - 16;
#pragma unroll
    for (int k = 0; k < 4; ++k) {
      int j = b2 * 1024 + tid + k * 256;          // j = o2*1024 + d
      int o = j >> 10, d = j & 1023;
      wpT[j] = f2bs(Wp[d * 64 + o]);
    }
  }
}

// ---------------------------------------------------------------------------
// K1 (32x32 MFMA): per (bh,chunk): K=elu1(x Wk), V=x Wv
//   mir [o][e] = (K^T V)^T bf16 ; zmir [e] = colsum(K) bf16 (via ones-MFMA)
// Wave w -> quadrant (wr=w>>1, wc=w&1). ONE barrier.
// ---------------------------------------------------------------------------
__global__ __launch_bounds__(256) void k_chunk_state(
    const float* __restrict__ x, const unsigned short* __restrict__ wkT,
    const unsigned short* __restrict__ wvT, unsigned short* __restrict__ mir,
    unsigned short* __restrict__ zmir)
{
  __shared__ __align__(16) unsigned short Kt[64][72];   // K^T[e][t] (elu'd)
  __shared__ __align__(16) unsigned short Vt[64][72];   // V^T[o][t]

  const int tid = threadIdx.x, blk = blockIdx.x;
  const int c = blk & 63, bh = blk >> 6, h = bh & 15, b = bh >> 4;
  const int l = tid & 63, w = tid >> 6;
  const int wr = w >> 1, wc = w & 1;
  const int l31 = l & 31, g = l >> 5;

  // x fragments: rows t = wr*32 + l31, k-slices d = j*16 + g*8
  const float* xr = x + ((size_t)(b * Sv + c * 64 + wr * 32 + l31)) * 1024 + h * 64;
  bf16x8 xa[4];
#pragma unroll
  for (int j = 0; j < 4; ++j) {
    float4 u0 = *(const float4*)(xr + j * 16 + g * 8);
    float4 u1 = *(const float4*)(xr + j * 16 + g * 8 + 4);
    xa[j] = pack8(u0, u1);
  }

  // K ladder -> Kt[e][t] (packed by 4 along t)
  {
    const unsigned short* wk = wkT + h * 4096;
    f32x16 acc = zero16();
#pragma unroll
    for (int j = 0; j < 4; ++j) {
      bf16x8 bb = *(const bf16x8*)(wk + (wc * 32 + l31) * 64 + j * 16 + g * 8);
      acc = MFMA32(xa[j], bb, acc);
    }
#pragma unroll
    for (int q4 = 0; q4 < 4; ++q4) {
      u16x4 p;
#pragma unroll
      for (int i = 0; i < 4; ++i) p[i] = f2bs(elu1(acc[q4 * 4 + i]));
      *(u16x4*)&Kt[wc * 32 + l31][wr * 32 + 8 * q4 + 4 * g] = p;
    }
  }
  // V ladder -> Vt[o][t] (packed by 4 along t)
  {
    const unsigned short* wv = wvT + h * 4096;
    f32x16 acc = zero16();
#pragma unroll
    for (int j = 0; j < 4; ++j) {
      bf16x8 bb = *(const bf16x8*)(wv + (wc * 32 + l31) * 64 + j * 16 + g * 8);
      acc = MFMA32(xa[j], bb, acc);
    }
#pragma unroll
    for (int q4 = 0; q4 < 4; ++q4) {
      u16x4 p;
#pragma unroll
      for (int i = 0; i < 4; ++i) p[i] = f2bs(acc[q4 * 4 + i]);
      *(u16x4*)&Vt[wc * 32 + l31][wr * 32 + 8 * q4 + 4 * g] = p;
    }
  }
  __syncthreads();

  // KtV: D[e][o] = sum_t K^T[e][t] V[t][o];  z[e] = ones . K (col-replicated)
  f32x16 sacc = zero16(), zacc = zero16();
  const bf16x8 one = ones8();
#pragma unroll
  for (int j = 0; j < 4; ++j) {
    bf16x8 aK = *(const bf16x8*)&Kt[wr * 32 + l31][j * 16 + g * 8];
    bf16x8 vB = *(const bf16x8*)&Vt[wc * 32 + l31][j * 16 + g * 8];
    sacc = MFMA32(aK, vB, sacc);
    bf16x8 kB = *(const bf16x8*)&Kt[wc * 32 + l31][j * 16 + g * 8];
    zacc = MFMA32(one, kB, zacc);
  }
  // mir[o][e], packed by 4 along e
  unsigned short* mp = mir + (size_t)blk * 4096;
#pragma unroll
  for (int q4 = 0; q4 < 4; ++q4) {
    u16x4 p;
#pragma unroll
    for (int i = 0; i < 4; ++i) p[i] = f2bs(sacc[q4 * 4 + i]);
    *(u16x4*)&mp[(size_t)(wc * 32 + l31) * 64 + wr * 32 + 8 * q4 + 4 * g] = p;
  }
  // z write: waves 0,1 (wr==0), lane group g==0, value replicated over rows
  if (w < 2 && g == 0)
    zmir[(size_t)blk * 64 + wc * 32 + l31] = f2bs(zacc[0]);
}

// ---------------------------------------------------------------------------
// K2: exclusive prefix over chunks — loads up-front, register scan, stores.
// ---------------------------------------------------------------------------
__global__ __launch_bounds__(256) void k_prefix(
    unsigned short* __restrict__ mir, unsigned short* __restrict__ zmir)
{
  const int bh = blockIdx.x / 17, g = blockIdx.x % 17;
  const int tid = threadIdx.x;
  if (g < 16) {
    size_t base = (size_t)bh * 64 * 4096 + g * 256 + tid;
    unsigned short v[64];
#pragma unroll
    for (int cc = 0; cc < 64; ++cc) v[cc] = mir[base + (size_t)cc * 4096];
    float carry = 0.f;
#pragma unroll
    for (int cc = 0; cc < 64; ++cc) {
      float f = b2f(v[cc]);
      v[cc] = f2bs(carry);
      carry += f;
    }
#pragma unroll
    for (int cc = 0; cc < 64; ++cc) mir[base + (size_t)cc * 4096] = v[cc];
  } else if (tid < 64) {
    size_t base = (size_t)bh * 64 * 64 + tid;
    unsigned short v[64];
#pragma unroll
    for (int cc = 0; cc < 64; ++cc) v[cc] = zmir[base + (size_t)cc * 64];
    float carry = 0.f;
#pragma unroll
    for (int cc = 0; cc < 64; ++cc) {
      float f = b2f(v[cc]);
      v[cc] = f2bs(carry);
      carry += f;
    }
#pragma unroll
    for (int cc = 0; cc < 64; ++cc) zmir[base + (size_t)cc * 64] = v[cc];
  }
}

// ---------------------------------------------------------------------------
// K3 (32x32 MFMA, transposed-compute): per (b,h,chunk):
//   y = (Q Sprev + tril(Q K^T) V) / (q.zprev + rowsum(A) + eps)
// Every staged product computed output-transposed (swapped MFMA operands)
// so ALL stage writes are packed u16x4. dacc row-replicated -> ONE rcp.
// y stage+store wave-private -> 3 barriers (was 4), zero scalar ds_write.
// ---------------------------------------------------------------------------
__global__ __launch_bounds__(256) void k_y(
    const float* __restrict__ x, const unsigned short* __restrict__ wqT,
    const unsigned short* __restrict__ wkT, const unsigned short* __restrict__ wvT,
    const unsigned short* __restrict__ mir, const unsigned short* __restrict__ zmir,
    unsigned short* __restrict__ y)
{
  __shared__ __align__(16) unsigned short Qb[64][72];   // Q[t][e] -> A[t][s]
  __shared__ __align__(16) unsigned short Kb[64][72];   // K[s][e] -> y[t][o]
  __shared__ __align__(16) unsigned short Vt[64][72];   // V^T[o][t]

  const int tid = threadIdx.x, blk = blockIdx.x;
  const int c = blk & 63, bh = blk >> 6, h = bh & 15, b = bh >> 4;
  const int l = tid & 63, w = tid >> 6;
  const int wr = w >> 1, wc = w & 1;
  const int l31 = l & 31, g = l >> 5;
  const size_t sblk = (size_t)blk;

  // x fragments: rows t = wr*32 + l31
  const float* xr = x + ((size_t)(b * Sv + c * 64 + wr * 32 + l31)) * 1024 + h * 64;
  bf16x8 xa[4];
#pragma unroll
  for (int j = 0; j < 4; ++j) {
    float4 u0 = *(const float4*)(xr + j * 16 + g * 8);
    float4 u1 = *(const float4*)(xr + j * 16 + g * 8 + 4);
    xa[j] = pack8(u0, u1);
  }

  // Q^T ladder: D[o][t] = MFMA(WqT-rows, x) -> packed stage Q[t][e]
  {
    const unsigned short* wq = wqT + h * 4096;
    f32x16 acc = zero16();
#pragma unroll
    for (int j = 0; j < 4; ++j) {
      bf16x8 aW = *(const bf16x8*)(wq + (wc * 32 + l31) * 64 + j * 16 + g * 8);
      acc = MFMA32(aW, xa[j], acc);
    }
#pragma unroll
    for (int q4 = 0; q4 < 4; ++q4) {
      u16x4 p;
#pragma unroll
      for (int i = 0; i < 4; ++i) p[i] = f2bs(elu1(acc[q4 * 4 + i]));
      *(u16x4*)&Qb[wr * 32 + l31][wc * 32 + 8 * q4 + 4 * g] = p;
    }
  }
  // K^T ladder -> packed stage K[s][e]
  {
    const unsigned short* wk = wkT + h * 4096;
    f32x16 acc = zero16();
#pragma unroll
    for (int j = 0; j < 4; ++j) {
      bf16x8 aW = *(const bf16x8*)(wk + (wc * 32 + l31) * 64 + j * 16 + g * 8);
      acc = MFMA32(aW, xa[j], acc);
    }
#pragma unroll
    for (int q4 = 0; q4 < 4; ++q4) {
      u16x4 p;
#pragma unroll
      for (int i = 0; i < 4; ++i) p[i] = f2bs(elu1(acc[q4 * 4 + i]));
      *(u16x4*)&Kb[wr * 32 + l31][wc * 32 + 8 * q4 + 4 * g] = p;
    }
  }
  // V ladder (unswapped) -> Vt[o][t] (packed by 4 along t)
  {
    const unsigned short* wv = wvT + h * 4096;
    f32x16 acc = zero16();
#pragma unroll
    for (int j = 0; j < 4; ++j) {
      bf16x8 bb = *(const bf16x8*)(wv + (wc * 32 + l31) * 64 + j * 16 + g * 8);
      acc = MFMA32(xa[j], bb, acc);
    }
#pragma unroll
    for (int q4 = 0; q4 < 4; ++q4) {
      u16x4 p;
#pragma unroll
      for (int i = 0; i < 4; ++i) p[i] = f2bs(acc[q4 * 4 + i]);
      *(u16x4*)&Vt[wc * 32 + l31][wr * 32 + 8 * q4 + 4 * g] = p;
    }
  }
  __syncthreads();   // bar1: Q,K,V^T staged

  // Q fragments (rows t = wr*32 + l31, full e) — cross-wave read
  bf16x8 qa[4];
#pragma unroll
  for (int j = 0; j < 4; ++j)
    qa[j] = *(const bf16x8*)&Qb[wr * 32 + l31][j * 16 + g * 8];
  // z splat fragments (lane-row independent)
  const unsigned short* zp = zmir + sblk * 64;
  bf16x8 zf[4];
#pragma unroll
  for (int j = 0; j < 4; ++j)
    zf[j] = *(const bf16x8*)(zp + j * 16 + g * 8);

  // y^T (QS part): D[o][t] = MFMA(S^T-rows, Q);  den: D[*][t] = MFMA(z-splat, Q)
  // A^T: D[s][t] = MFMA(K-rows, Q)
  const unsigned short* sp = mir + sblk * 4096;
  f32x16 aacc = zero16(), nacc = zero16(), dacc = zero16();
#pragma unroll
  for (int j = 0; j < 4; ++j) {
    bf16x8 sA = *(const bf16x8*)(sp + (size_t)(wc * 32 + l31) * 64 + j * 16 + g * 8);
    nacc = MFMA32(sA, qa[j], nacc);
    dacc = MFMA32(zf[j], qa[j], dacc);
  }
  if (w != 1) {  // wave 1 (t<32, s>=32) strictly upper -> A quadrant = 0
#pragma unroll
    for (int j = 0; j < 4; ++j) {
      bf16x8 kA = *(const bf16x8*)&Kb[wc * 32 + l31][j * 16 + g * 8];
      aacc = MFMA32(kA, qa[j], aacc);
    }
    if (w == 0 || w == 3) {  // diagonal: zero s > t  (s=pattern, t=l31)
#pragma unroll
      for (int r = 0; r < 16; ++r)
        if ((r & 3) + 8 * (r >> 2) + 4 * g > l31) aacc[r] = 0.f;
    }
  }
  __syncthreads();   // bar2: all waves done reading Qb(Q) / Kb(K)

  // stage A[t][s] (A^T rows s=pattern, col t=l31 -> packed along s at row t)
  if (w != 1) {
#pragma unroll
    for (int q4 = 0; q4 < 4; ++q4) {
      u16x4 p;
#pragma unroll
      for (int i = 0; i < 4; ++i) p[i] = f2bs(aacc[q4 * 4 + i]);
      *(u16x4*)&Qb[wr * 32 + l31][wc * 32 + 8 * q4 + 4 * g] = p;
    }
  }
  __syncthreads();   // bar3: A staged

  // y^T += V^T-rows . A ; den += ones . A (row-replicated rowsum)
  const bf16x8 one = ones8();
  const int jmax = (wr == 0) ? 2 : 4;   // t<32 -> only s<32 contributes
#pragma unroll
  for (int j = 0; j < 4; ++j) {
    if (j >= jmax) break;
    bf16x8 aA = *(const bf16x8*)&Qb[wr * 32 + l31][j * 16 + g * 8];
    bf16x8 vA = *(const bf16x8*)&Vt[wc * 32 + l31][j * 16 + g * 8];
    nacc = MFMA32(vA, aA, nacc);
    dacc = MFMA32(one, aA, dacc);
  }

  // ONE rcp per lane (dacc row-replicated: den of row t = wr*32+l31)
  const float invd = __builtin_amdgcn_rcpf(dacc[0] + 1e-6f);
  // stage y[t][o] packed (y^T rows o=pattern, col t=l31) — wave-private region
#pragma unroll
  for (int q4 = 0; q4 < 4; ++q4) {
    u16x4 p;
#pragma unroll
    for (int i = 0; i < 4; ++i) p[i] = f2bs(nacc[q4 * 4 + i] * invd);
    *(u16x4*)&Kb[wr * 32 + l31][wc * 32 + 8 * q4 + 4 * g] = p;
  }
  // wave-private coalesced store (in-wave DS order; NO barrier)
  unsigned short* yb = y + ((size_t)(b * Sv + c * 64)) * 1024 + h * 64;
#pragma unroll
  for (int i = 0; i < 2; ++i) {
    int unit = l + i * 64;
    int t_loc = unit >> 2, seg = unit & 3;
    uint4 q = *(const uint4*)&Kb[wr * 32 + t_loc][wc * 32 + seg * 8];
    *(uint4*)&yb[(size_t)(wr * 32 + t_loc) * 1024 + wc * 32 + seg * 8] = q;
  }
}

// ---------------------------------------------------------------------------
// K4 (32x32 MFMA): out = y @ Wp. 64 rows/block, 4 waves = quadrants,
// K=1024 as two independent accumulator chains. LDS-free, barrier-free.
// ---------------------------------------------------------------------------
__global__ __launch_bounds__(256) void k_proj(
    const unsigned short* __restrict__ y, const unsigned short* __restrict__ wpT,
    float* __restrict__ out)
{
  const int tid = threadIdx.x, bid = blockIdx.x;
  const int l = tid & 63, w = tid >> 6;
  const int wr = w >> 1, wc = w & 1;
  const int l31 = l & 31, g = l >> 5;
  const size_t row0 = (size_t)bid * 64;

  const unsigned short* yrow = y + (row0 + wr * 32 + l31) * 1024 + g * 8;
  const unsigned short* wpr = wpT + (size_t)(wc * 32 + l31) * 1024 + g * 8;

  f32x16 acc0 = zero16(), acc1 = zero16();
#pragma unroll 4
  for (int jj = 0; jj < 64; jj += 2) {
    bf16x8 a0 = *(const bf16x8*)(yrow + jj * 16);
    bf16x8 b0 = *(const bf16x8*)(wpr + jj * 16);
    acc0 = MFMA32(a0, b0, acc0);
    bf16x8 a1 = *(const bf16x8*)(yrow + jj * 16 + 16);
    bf16x8 b1 = *(const bf16x8*)(wpr + jj * 16 + 16);
    acc1 = MFMA32(a1, b1, acc1);
  }
  float* op = out + (row0 + wr * 32) * 64 + wc * 32;
#pragma unroll
  for (int r = 0; r < 16; ++r)
    op[(size_t)((r & 3) + 8 * (r >> 2) + 4 * g) * 64 + l31] = acc0[r] + acc1[r];
}

// ---------------------------------------------------------------------------
extern "C" void kernel_launch(void* const* d_in, const int* in_sizes, int n_in,
                              void* d_out, int out_size, void* d_ws, size_t ws_size,
                              hipStream_t stream)
{
  const float* x  = (const float*)d_in[0];
  const float* Wq = (const float*)d_in[1];
  const float* Wk = (const float*)d_in[2];
  const float* Wv = (const float*)d_in[3];
  const float* Wp = (const float*)d_in[4];
  float* out = (float*)d_out;

  // ws layout: mir bf16 33.55 MB | zmir bf16 0.52 | wqT/wkT/wvT/wpT 0.52 |
  //            y bf16 [16384][1024] 33.55 MB      (total ~68 MB)
  unsigned short* mir = (unsigned short*)d_ws;
  unsigned short* zmir = mir + 16777216;
  unsigned short* wqT = zmir + 262144;
  unsigned short* wkT = wqT + 65536;
  unsigned short* wvT = wkT + 65536;
  unsigned short* wpT = wvT + 65536;
  unsigned short* yb  = wpT + 65536;

  hipLaunchKernelGGL(k_prep_w, dim3(80), dim3(256), 0, stream,
                     Wq, Wk, Wv, Wp, wqT, wkT, wvT, wpT);
  hipLaunchKernelGGL(k_chunk_state, dim3(BHv * NCv), dim3(256), 0, stream,
                     x, wkT, wvT, mir, zmir);
  hipLaunchKernelGGL(k_prefix, dim3(BHv * 17), dim3(256), 0, stream, mir, zmir);
  hipLaunchKernelGGL(k_y, dim3(BHv * NCv), dim3(256), 0, stream,
                     x, wqT, wkT, wvT, mir, zmir, yb);
  hipLaunchKernelGGL(k_proj, dim3((Bv * Sv) / 64), dim3(256), 0, stream,
                     yb, wpT, out);
}

// Round 16
// 95.063 us; speedup vs baseline: 1.7475x; 1.4270x over previous
//
#include <hip/hip_runtime.h>
#include <hip/hip_bf16.h>

// Problem constants
#define Bv 4
#define Sv 4096
#define Dv 1024
#define Hv 16
#define Ov 64
#define NCv 64
#define BHv 64

typedef __attribute__((ext_vector_type(8))) short bf16x8;
typedef __attribute__((ext_vector_type(4))) unsigned short u16x4;
typedef __attribute__((ext_vector_type(8))) unsigned short u16x8;
typedef __attribute__((ext_vector_type(4))) float f32x4;
typedef __attribute__((ext_vector_type(16))) float f32x16;
#define MFMA(a, b, c) __builtin_amdgcn_mfma_f32_16x16x32_bf16(a, b, c, 0, 0, 0)
#define MFMA32(a, b, c) __builtin_amdgcn_mfma_f32_32x32x16_bf16(a, b, c, 0, 0, 0)

__device__ __forceinline__ unsigned short f2bs(float f) {
  union { __hip_bfloat16 h; unsigned short u; } v;
  v.h = __float2bfloat16(f);
  return v.u;
}
__device__ __forceinline__ float b2f(unsigned short u) {
  union { unsigned u; float f; } v; v.u = ((unsigned)u) << 16; return v.f;
}
__device__ __forceinline__ float elu1(float a) {
  return a > 0.f ? a + 1.f : __expf(a);
}
__device__ __forceinline__ f32x4 zero4() {
  f32x4 v = {0.f, 0.f, 0.f, 0.f}; return v;
}
__device__ __forceinline__ f32x16 zero16() {
  f32x16 v;
#pragma unroll
  for (int i = 0; i < 16; ++i) v[i] = 0.f;
  return v;
}
__device__ __forceinline__ bf16x8 ones8() {
  union { u16x8 u; bf16x8 h; } r;
#pragma unroll
  for (int i = 0; i < 8; ++i) r.u[i] = 0x3F80;   // bf16 1.0
  return r.h;
}

// ---------------------------------------------------------------------------
// K0 prep: Wq/Wk/Wv [h][d][o] -> bf16 [h][o][d]; Wp [d][o2] -> bf16 [o2][d]
// ---------------------------------------------------------------------------
__global__ __launch_bounds__(256) void k_prep_w(
    const float* __restrict__ Wq, const float* __restrict__ Wk,
    const float* __restrict__ Wv, const float* __restrict__ Wp,
    unsigned short* __restrict__ wqT, unsigned short* __restrict__ wkT,
    unsigned short* __restrict__ wvT, unsigned short* __restrict__ wpT)
{
  const int blk = blockIdx.x, tid = threadIdx.x;
  if (blk < 16) {
    int h = blk;
    for (int j = tid; j < 4096; j += 256) {       // j = o*64 + d (output idx)
      int o = j >> 6, d = j & 63;
      int src = h * 4096 + d * 64 + o;
      wqT[h * 4096 + j] = f2bs(Wq[src]);
      wkT[h * 4096 + j] = f2bs(Wk[src]);
      wvT[h * 4096 + j] = f2bs(Wv[src]);
    }
  } else {
    int b2 = blk - 16;
#pragma unroll
    for (int k = 0; k < 4; ++k) {
      int j = b2 * 1024 + tid + k * 256;          // j = o2*1024 + d
      int o = j >> 10, d = j & 1023;
      wpT[j] = f2bs(Wp[d * 64 + o]);
    }
  }
}

// ---------------------------------------------------------------------------
// K1 (coalesced-staged): per (bh,chunk): K=elu1(x Wk), V=x Wv
//   mir [o][e] = (K^T V)^T bf16 ; zmir [e] = colsum(K) bf16
// ALL global accesses coalesced (weights/x staged in, mir staged out via LDS).
// ---------------------------------------------------------------------------
__global__ __launch_bounds__(256) void k_chunk_state(
    const float* __restrict__ x, const unsigned short* __restrict__ wkT,
    const unsigned short* __restrict__ wvT, unsigned short* __restrict__ mir,
    unsigned short* __restrict__ zmir)
{
  __shared__ __align__(16) unsigned short Xb[64][72];   // x tile -> mir stage
  __shared__ __align__(16) unsigned short Kt[64][72];   // WkT -> K^T[e][t]
  __shared__ __align__(16) unsigned short Vt[64][72];   // WvT -> V^T[o][t]

  const int tid = threadIdx.x, blk = blockIdx.x;
  const int c = blk & 63, bh = blk >> 6, h = bh & 15, b = bh >> 4;
  const int l = tid & 63, w = tid >> 6;
  const int wr = w >> 1, wc = w & 1;
  const int l31 = l & 31, g = l >> 5;

  // --- coalesced weight loads -> LDS ---
  const unsigned short* wkp = wkT + h * 4096;
  const unsigned short* wvp = wvT + h * 4096;
#pragma unroll
  for (int it = 0; it < 2; ++it) {
    int j = tid * 8 + it * 2048;
    int r = j >> 6, col = j & 63;
    *(uint4*)&Kt[r][col] = *(const uint4*)&wkp[j];
    *(uint4*)&Vt[r][col] = *(const uint4*)&wvp[j];
  }
  // --- coalesced x load (f32, per-row 256B segments) + cvt -> Xb ---
  const float* xbase = x + ((size_t)(b * Sv + c * 64)) * 1024 + h * 64;
#pragma unroll
  for (int it = 0; it < 4; ++it) {
    int u = tid + it * 256;
    int r = u >> 4, seg = u & 15;
    float4 f = *(const float4*)(xbase + (size_t)r * 1024 + seg * 4);
    u16x4 p; p[0] = f2bs(f.x); p[1] = f2bs(f.y); p[2] = f2bs(f.z); p[3] = f2bs(f.w);
    *(u16x4*)&Xb[r][seg * 4] = p;
  }
  __syncthreads();   // bar0: staging done

  // fragments from LDS
  bf16x8 xa[4], wkf[4], wvf[4];
#pragma unroll
  for (int j = 0; j < 4; ++j) {
    xa[j]  = *(const bf16x8*)&Xb[wr * 32 + l31][j * 16 + g * 8];
    wkf[j] = *(const bf16x8*)&Kt[wc * 32 + l31][j * 16 + g * 8];
    wvf[j] = *(const bf16x8*)&Vt[wc * 32 + l31][j * 16 + g * 8];
  }
  // K, V ladders (normal orientation: D[t][e])
  f32x16 kacc = zero16(), vacc = zero16();
#pragma unroll
  for (int j = 0; j < 4; ++j) {
    kacc = MFMA32(xa[j], wkf[j], kacc);
    vacc = MFMA32(xa[j], wvf[j], vacc);
  }
  __syncthreads();   // bar1: weights consumed

  // stage K^T[e][t] / V^T[o][t], packed along t
#pragma unroll
  for (int q4 = 0; q4 < 4; ++q4) {
    u16x4 pk, pv;
#pragma unroll
    for (int i = 0; i < 4; ++i) {
      pk[i] = f2bs(elu1(kacc[q4 * 4 + i]));
      pv[i] = f2bs(vacc[q4 * 4 + i]);
    }
    *(u16x4*)&Kt[wc * 32 + l31][wr * 32 + 8 * q4 + 4 * g] = pk;
    *(u16x4*)&Vt[wc * 32 + l31][wr * 32 + 8 * q4 + 4 * g] = pv;
  }
  __syncthreads();   // bar2: K^T, V^T staged

  // KtV: D[e][o]; z = ones . K^T-cols (col-replicated)
  f32x16 sacc = zero16(), zacc = zero16();
  const bf16x8 one = ones8();
#pragma unroll
  for (int j = 0; j < 4; ++j) {
    bf16x8 aK = *(const bf16x8*)&Kt[wr * 32 + l31][j * 16 + g * 8];
    bf16x8 vB = *(const bf16x8*)&Vt[wc * 32 + l31][j * 16 + g * 8];
    sacc = MFMA32(aK, vB, sacc);
    bf16x8 kB = *(const bf16x8*)&Kt[wc * 32 + l31][j * 16 + g * 8];
    zacc = MFMA32(one, kB, zacc);
  }
  // stage mir[o][e] into Xb (packed along e): row o = wc*32+l31, cols e
#pragma unroll
  for (int q4 = 0; q4 < 4; ++q4) {
    u16x4 p;
#pragma unroll
    for (int i = 0; i < 4; ++i) p[i] = f2bs(sacc[q4 * 4 + i]);
    *(u16x4*)&Xb[wc * 32 + l31][wr * 32 + 8 * q4 + 4 * g] = p;
  }
  __syncthreads();   // bar3: mir staged

  // coalesced mir store
  unsigned short* mp = mir + (size_t)blk * 4096;
#pragma unroll
  for (int it = 0; it < 2; ++it) {
    int j = tid * 8 + it * 2048;
    int r = j >> 6, col = j & 63;
    *(uint4*)&mp[j] = *(const uint4*)&Xb[r][col];
  }
  if (w < 2 && g == 0)
    zmir[(size_t)blk * 64 + wc * 32 + l31] = f2bs(zacc[0]);
}

// ---------------------------------------------------------------------------
// K2: exclusive prefix over chunks — loads up-front, register scan, stores.
// ---------------------------------------------------------------------------
__global__ __launch_bounds__(256) void k_prefix(
    unsigned short* __restrict__ mir, unsigned short* __restrict__ zmir)
{
  const int bh = blockIdx.x / 17, g = blockIdx.x % 17;
  const int tid = threadIdx.x;
  if (g < 16) {
    size_t base = (size_t)bh * 64 * 4096 + g * 256 + tid;
    unsigned short v[64];
#pragma unroll
    for (int cc = 0; cc < 64; ++cc) v[cc] = mir[base + (size_t)cc * 4096];
    float carry = 0.f;
#pragma unroll
    for (int cc = 0; cc < 64; ++cc) {
      float f = b2f(v[cc]);
      v[cc] = f2bs(carry);
      carry += f;
    }
#pragma unroll
    for (int cc = 0; cc < 64; ++cc) mir[base + (size_t)cc * 4096] = v[cc];
  } else if (tid < 64) {
    size_t base = (size_t)bh * 64 * 64 + tid;
    unsigned short v[64];
#pragma unroll
    for (int cc = 0; cc < 64; ++cc) v[cc] = zmir[base + (size_t)cc * 64];
    float carry = 0.f;
#pragma unroll
    for (int cc = 0; cc < 64; ++cc) {
      float f = b2f(v[cc]);
      v[cc] = f2bs(carry);
      carry += f;
    }
#pragma unroll
    for (int cc = 0; cc < 64; ++cc) zmir[base + (size_t)cc * 64] = v[cc];
  }
}

// ---------------------------------------------------------------------------
// K3 (coalesced-staged, transposed-compute): per (b,h,chunk):
//   y = (Q Sprev + tril(Q K^T) V) / (q.zprev + rowsum(A) + eps)
// Weights/x/mir all enter via coalesced loads; fragments from LDS.
// Stage orientations identical to (verified) round-15 kernel.
// ---------------------------------------------------------------------------
__global__ __launch_bounds__(256) void k_y(
    const float* __restrict__ x, const unsigned short* __restrict__ wqT,
    const unsigned short* __restrict__ wkT, const unsigned short* __restrict__ wvT,
    const unsigned short* __restrict__ mir, const unsigned short* __restrict__ zmir,
    unsigned short* __restrict__ y)
{
  __shared__ __align__(16) unsigned short Xb[64][72];   // x -> mir[o][e]
  __shared__ __align__(16) unsigned short Qb[64][72];   // WqT -> Q[t][e] -> A[t][s]
  __shared__ __align__(16) unsigned short Kb[64][72];   // WkT -> K[s][e] -> y[t][o]
  __shared__ __align__(16) unsigned short Vt[64][72];   // WvT -> V^T[o][t]

  const int tid = threadIdx.x, blk = blockIdx.x;
  const int c = blk & 63, bh = blk >> 6, h = bh & 15, b = bh >> 4;
  const int l = tid & 63, w = tid >> 6;
  const int wr = w >> 1, wc = w & 1;
  const int l31 = l & 31, g = l >> 5;
  const size_t sblk = (size_t)blk;

  // --- early coalesced mir load -> regs (hides under staging) ---
  const unsigned short* mp = mir + sblk * 4096;
  uint4 mreg[2];
#pragma unroll
  for (int it = 0; it < 2; ++it)
    mreg[it] = *(const uint4*)&mp[tid * 8 + it * 2048];
  // z splat fragments (lane-group-uniform 16B loads)
  const unsigned short* zp = zmir + sblk * 64;
  bf16x8 zf[4];
#pragma unroll
  for (int j = 0; j < 4; ++j)
    zf[j] = *(const bf16x8*)(zp + j * 16 + g * 8);

  // --- coalesced weight loads -> LDS ---
  const unsigned short* wqp = wqT + h * 4096;
  const unsigned short* wkp = wkT + h * 4096;
  const unsigned short* wvp = wvT + h * 4096;
#pragma unroll
  for (int it = 0; it < 2; ++it) {
    int j = tid * 8 + it * 2048;
    int r = j >> 6, col = j & 63;
    *(uint4*)&Qb[r][col] = *(const uint4*)&wqp[j];
    *(uint4*)&Kb[r][col] = *(const uint4*)&wkp[j];
    *(uint4*)&Vt[r][col] = *(const uint4*)&wvp[j];
  }
  // --- coalesced x load + cvt -> Xb ---
  const float* xbase = x + ((size_t)(b * Sv + c * 64)) * 1024 + h * 64;
#pragma unroll
  for (int it = 0; it < 4; ++it) {
    int u = tid + it * 256;
    int r = u >> 4, seg = u & 15;
    float4 f = *(const float4*)(xbase + (size_t)r * 1024 + seg * 4);
    u16x4 p; p[0] = f2bs(f.x); p[1] = f2bs(f.y); p[2] = f2bs(f.z); p[3] = f2bs(f.w);
    *(u16x4*)&Xb[r][seg * 4] = p;
  }
  __syncthreads();   // bar0: staging done

  // fragments from LDS
  bf16x8 xa[4], wqf[4], wkf[4], wvf[4];
#pragma unroll
  for (int j = 0; j < 4; ++j) {
    xa[j]  = *(const bf16x8*)&Xb[wr * 32 + l31][j * 16 + g * 8];
    wqf[j] = *(const bf16x8*)&Qb[wc * 32 + l31][j * 16 + g * 8];
    wkf[j] = *(const bf16x8*)&Kb[wc * 32 + l31][j * 16 + g * 8];
    wvf[j] = *(const bf16x8*)&Vt[wc * 32 + l31][j * 16 + g * 8];
  }
  // Q^T, K^T ladders (transposed: D[e][t] / D[e][s]); V ladder (normal D[t][o])
  f32x16 qacc = zero16(), kacc = zero16(), vacc = zero16();
#pragma unroll
  for (int j = 0; j < 4; ++j) {
    qacc = MFMA32(wqf[j], xa[j], qacc);
    kacc = MFMA32(wkf[j], xa[j], kacc);
    vacc = MFMA32(xa[j], wvf[j], vacc);
  }
  __syncthreads();   // bar1: weights + x consumed

  // stage Q[t][e], K[s][e], V^T[o][t] (all packed); mir regs -> Xb[o][e]
#pragma unroll
  for (int q4 = 0; q4 < 4; ++q4) {
    u16x4 pq, pk, pv;
#pragma unroll
    for (int i = 0; i < 4; ++i) {
      pq[i] = f2bs(elu1(qacc[q4 * 4 + i]));
      pk[i] = f2bs(elu1(kacc[q4 * 4 + i]));
      pv[i] = f2bs(vacc[q4 * 4 + i]);
    }
    *(u16x4*)&Qb[wr * 32 + l31][wc * 32 + 8 * q4 + 4 * g] = pq;
    *(u16x4*)&Kb[wr * 32 + l31][wc * 32 + 8 * q4 + 4 * g] = pk;
    *(u16x4*)&Vt[wc * 32 + l31][wr * 32 + 8 * q4 + 4 * g] = pv;
  }
#pragma unroll
  for (int it = 0; it < 2; ++it) {
    int j = tid * 8 + it * 2048;
    int r = j >> 6, col = j & 63;
    *(uint4*)&Xb[r][col] = mreg[it];
  }
  __syncthreads();   // bar2: Q,K,V^T,mir staged

  // qa fragments (rows t = wr*32 + l31, full e)
  bf16x8 qa[4];
#pragma unroll
  for (int j = 0; j < 4; ++j)
    qa[j] = *(const bf16x8*)&Qb[wr * 32 + l31][j * 16 + g * 8];

  // y^T (QS): D[o][t] = MFMA(S^T-rows, Q); den: MFMA(z-splat, Q); A^T: MFMA(K, Q)
  f32x16 aacc = zero16(), nacc = zero16(), dacc = zero16();
#pragma unroll
  for (int j = 0; j < 4; ++j) {
    bf16x8 sA = *(const bf16x8*)&Xb[wc * 32 + l31][j * 16 + g * 8];
    nacc = MFMA32(sA, qa[j], nacc);
    dacc = MFMA32(zf[j], qa[j], dacc);
  }
  if (w != 1) {  // wave 1 (t<32, s>=32) strictly upper -> A quadrant = 0
#pragma unroll
    for (int j = 0; j < 4; ++j) {
      bf16x8 kA = *(const bf16x8*)&Kb[wc * 32 + l31][j * 16 + g * 8];
      aacc = MFMA32(kA, qa[j], aacc);
    }
    if (w == 0 || w == 3) {  // diagonal: zero s > t (s=pattern, t=l31)
#pragma unroll
      for (int r = 0; r < 16; ++r)
        if ((r & 3) + 8 * (r >> 2) + 4 * g > l31) aacc[r] = 0.f;
    }
  }
  __syncthreads();   // bar3: Qb(Q) / Kb(K) consumed

  // stage A[t][s] packed
  if (w != 1) {
#pragma unroll
    for (int q4 = 0; q4 < 4; ++q4) {
      u16x4 p;
#pragma unroll
      for (int i = 0; i < 4; ++i) p[i] = f2bs(aacc[q4 * 4 + i]);
      *(u16x4*)&Qb[wr * 32 + l31][wc * 32 + 8 * q4 + 4 * g] = p;
    }
  }
  __syncthreads();   // bar4: A staged

  // y^T += V^T-rows . A ; den += ones . A (row-replicated rowsum)
  const bf16x8 one = ones8();
  const int jmax = (wr == 0) ? 2 : 4;   // t<32 -> only s<32 contributes
#pragma unroll
  for (int j = 0; j < 4; ++j) {
    if (j >= jmax) break;
    bf16x8 aA = *(const bf16x8*)&Qb[wr * 32 + l31][j * 16 + g * 8];
    bf16x8 vA = *(const bf16x8*)&Vt[wc * 32 + l31][j * 16 + g * 8];
    nacc = MFMA32(vA, aA, nacc);
    dacc = MFMA32(one, aA, dacc);
  }

  // ONE rcp per lane (dacc row-replicated; den of row t = wr*32+l31)
  const float invd = __builtin_amdgcn_rcpf(dacc[0] + 1e-6f);
  // stage y[t][o] packed — wave-private quadrant
#pragma unroll
  for (int q4 = 0; q4 < 4; ++q4) {
    u16x4 p;
#pragma unroll
    for (int i = 0; i < 4; ++i) p[i] = f2bs(nacc[q4 * 4 + i] * invd);
    *(u16x4*)&Kb[wr * 32 + l31][wc * 32 + 8 * q4 + 4 * g] = p;
  }
  // wave-private coalesced store (in-wave DS order; NO barrier)
  unsigned short* yb = y + ((size_t)(b * Sv + c * 64)) * 1024 + h * 64;
#pragma unroll
  for (int i = 0; i < 2; ++i) {
    int unit = l + i * 64;
    int t_loc = unit >> 2, seg = unit & 3;
    uint4 q = *(const uint4*)&Kb[wr * 32 + t_loc][wc * 32 + seg * 8];
    *(uint4*)&yb[(size_t)(wr * 32 + t_loc) * 1024 + wc * 32 + seg * 8] = q;
  }
}

// ---------------------------------------------------------------------------
// K4 (32x32 MFMA): out = y @ Wp. 64 rows/block, 4 waves = quadrants,
// K=1024 as two independent accumulator chains. LDS-free, barrier-free.
// ---------------------------------------------------------------------------
__global__ __launch_bounds__(256) void k_proj(
    const unsigned short* __restrict__ y, const unsigned short* __restrict__ wpT,
    float* __restrict__ out)
{
  const int tid = threadIdx.x, bid = blockIdx.x;
  const int l = tid & 63, w = tid >> 6;
  const int wr = w >> 1, wc = w & 1;
  const int l31 = l & 31, g = l >> 5;
  const size_t row0 = (size_t)bid * 64;

  const unsigned short* yrow = y + (row0 + wr * 32 + l31) * 1024 + g * 8;
  const unsigned short* wpr = wpT + (size_t)(wc * 32 + l31) * 1024 + g * 8;

  f32x16 acc0 = zero16(), acc1 = zero16();
#pragma unroll 4
  for (int jj = 0; jj < 64; jj += 2) {
    bf16x8 a0 = *(const bf16x8*)(yrow + jj * 16);
    bf16x8 b0 = *(const bf16x8*)(wpr + jj * 16);
    acc0 = MFMA32(a0, b0, acc0);
    bf16x8 a1 = *(const bf16x8*)(yrow + jj * 16 + 16);
    bf16x8 b1 = *(const bf16x8*)(wpr + jj * 16 + 16);
    acc1 = MFMA32(a1, b1, acc1);
  }
  float* op = out + (row0 + wr * 32) * 64 + wc * 32;
#pragma unroll
  for (int r = 0; r < 16; ++r)
    op[(size_t)((r & 3) + 8 * (r >> 2) + 4 * g) * 64 + l31] = acc0[r] + acc1[r];
}

// ---------------------------------------------------------------------------
extern "C" void kernel_launch(void* const* d_in, const int* in_sizes, int n_in,
                              void* d_out, int out_size, void* d_ws, size_t ws_size,
                              hipStream_t stream)
{
  const float* x  = (const float*)d_in[0];
  const float* Wq = (const float*)d_in[1];
  const float* Wk = (const float*)d_in[2];
  const float* Wv = (const float*)d_in[3];
  const float* Wp = (const float*)d_in[4];
  float* out = (float*)d_out;

  // ws layout: mir bf16 33.55 MB | zmir bf16 0.52 | wqT/wkT/wvT/wpT 0.52 |
  //            y bf16 [16384][1024] 33.55 MB      (total ~68 MB)
  unsigned short* mir = (unsigned short*)d_ws;
  unsigned short* zmir = mir + 16777216;
  unsigned short* wqT = zmir + 262144;
  unsigned short* wkT = wqT + 65536;
  unsigned short* wvT = wkT + 65536;
  unsigned short* wpT = wvT + 65536;
  unsigned short* yb  = wpT + 65536;

  hipLaunchKernelGGL(k_prep_w, dim3(80), dim3(256), 0, stream,
                     Wq, Wk, Wv, Wp, wqT, wkT, wvT, wpT);
  hipLaunchKernelGGL(k_chunk_state, dim3(BHv * NCv), dim3(256), 0, stream,
                     x, wkT, wvT, mir, zmir);
  hipLaunchKernelGGL(k_prefix, dim3(BHv * 17), dim3(256), 0, stream, mir, zmir);
  hipLaunchKernelGGL(k_y, dim3(BHv * NCv), dim3(256), 0, stream,
                     x, wqT, wkT, wvT, mir, zmir, yb);
  hipLaunchKernelGGL(k_proj, dim3((Bv * Sv) / 64), dim3(256), 0, stream,
                     yb, wpT, out);
}

// Round 17
// 87.576 us; speedup vs baseline: 1.8968x; 1.0855x over previous
//
#include <hip/hip_runtime.h>
#include <hip/hip_bf16.h>

// Problem constants
#define Bv 4
#define Sv 4096
#define Dv 1024
#define Hv 16
#define Ov 64
#define NCv 64
#define BHv 64

typedef __attribute__((ext_vector_type(8))) short bf16x8;
typedef __attribute__((ext_vector_type(4))) unsigned short u16x4;
typedef __attribute__((ext_vector_type(8))) unsigned short u16x8;
typedef __attribute__((ext_vector_type(4))) float f32x4;
typedef __attribute__((ext_vector_type(16))) float f32x16;
#define MFMA32(a, b, c) __builtin_amdgcn_mfma_f32_32x32x16_bf16(a, b, c, 0, 0, 0)

__device__ __forceinline__ unsigned short f2bs(float f) {
  union { __hip_bfloat16 h; unsigned short u; } v;
  v.h = __float2bfloat16(f);
  return v.u;
}
__device__ __forceinline__ float b2f(unsigned short u) {
  union { unsigned u; float f; } v; v.u = ((unsigned)u) << 16; return v.f;
}
__device__ __forceinline__ float elu1(float a) {
  return a > 0.f ? a + 1.f : __expf(a);
}
__device__ __forceinline__ f32x16 zero16() {
  f32x16 v;
#pragma unroll
  for (int i = 0; i < 16; ++i) v[i] = 0.f;
  return v;
}
__device__ __forceinline__ bf16x8 ones8() {
  union { u16x8 u; bf16x8 h; } r;
#pragma unroll
  for (int i = 0; i < 8; ++i) r.u[i] = 0x3F80;   // bf16 1.0
  return r.h;
}

// ---------------------------------------------------------------------------
// K0 prep: Wq/Wk/Wv [h][d][o] -> bf16 [h][o][d]; Wp [d][o2] -> bf16 [o2][d]
// ---------------------------------------------------------------------------
__global__ __launch_bounds__(256) void k_prep_w(
    const float* __restrict__ Wq, const float* __restrict__ Wk,
    const float* __restrict__ Wv, const float* __restrict__ Wp,
    unsigned short* __restrict__ wqT, unsigned short* __restrict__ wkT,
    unsigned short* __restrict__ wvT, unsigned short* __restrict__ wpT)
{
  const int blk = blockIdx.x, tid = threadIdx.x;
  if (blk < 16) {
    int h = blk;
    for (int j = tid; j < 4096; j += 256) {       // j = o*64 + d (output idx)
      int o = j >> 6, d = j & 63;
      int src = h * 4096 + d * 64 + o;
      wqT[h * 4096 + j] = f2bs(Wq[src]);
      wkT[h * 4096 + j] = f2bs(Wk[src]);
      wvT[h * 4096 + j] = f2bs(Wv[src]);
    }
  } else {
    int b2 = blk - 16;
#pragma unroll
    for (int k = 0; k < 4; ++k) {
      int j = b2 * 1024 + tid + k * 256;          // j = o2*1024 + d
      int o = j >> 10, d = j & 1023;
      wpT[j] = f2bs(Wp[d * 64 + o]);
    }
  }
}

// ---------------------------------------------------------------------------
// K1 (coalesced-staged): per (bh,chunk): K=elu1(x Wk), V=x Wv
//   mir [o][e] = (K^T V)^T bf16 ; zmir [e] = colsum(K) bf16
// ---------------------------------------------------------------------------
__global__ __launch_bounds__(256) void k_chunk_state(
    const float* __restrict__ x, const unsigned short* __restrict__ wkT,
    const unsigned short* __restrict__ wvT, unsigned short* __restrict__ mir,
    unsigned short* __restrict__ zmir)
{
  __shared__ __align__(16) unsigned short Xb[64][72];   // x tile -> mir stage
  __shared__ __align__(16) unsigned short Kt[64][72];   // WkT -> K^T[e][t]
  __shared__ __align__(16) unsigned short Vt[64][72];   // WvT -> V^T[o][t]

  const int tid = threadIdx.x, blk = blockIdx.x;
  const int c = blk & 63, bh = blk >> 6, h = bh & 15, b = bh >> 4;
  const int l = tid & 63, w = tid >> 6;
  const int wr = w >> 1, wc = w & 1;
  const int l31 = l & 31, g = l >> 5;

  // --- coalesced weight loads -> LDS ---
  const unsigned short* wkp = wkT + h * 4096;
  const unsigned short* wvp = wvT + h * 4096;
#pragma unroll
  for (int it = 0; it < 2; ++it) {
    int j = tid * 8 + it * 2048;
    int r = j >> 6, col = j & 63;
    *(uint4*)&Kt[r][col] = *(const uint4*)&wkp[j];
    *(uint4*)&Vt[r][col] = *(const uint4*)&wvp[j];
  }
  // --- coalesced x load (f32, per-row 256B segments) + cvt -> Xb ---
  const float* xbase = x + ((size_t)(b * Sv + c * 64)) * 1024 + h * 64;
#pragma unroll
  for (int it = 0; it < 4; ++it) {
    int u = tid + it * 256;
    int r = u >> 4, seg = u & 15;
    float4 f = *(const float4*)(xbase + (size_t)r * 1024 + seg * 4);
    u16x4 p; p[0] = f2bs(f.x); p[1] = f2bs(f.y); p[2] = f2bs(f.z); p[3] = f2bs(f.w);
    *(u16x4*)&Xb[r][seg * 4] = p;
  }
  __syncthreads();   // bar0: staging done

  // fragments from LDS
  bf16x8 xa[4], wkf[4], wvf[4];
#pragma unroll
  for (int j = 0; j < 4; ++j) {
    xa[j]  = *(const bf16x8*)&Xb[wr * 32 + l31][j * 16 + g * 8];
    wkf[j] = *(const bf16x8*)&Kt[wc * 32 + l31][j * 16 + g * 8];
    wvf[j] = *(const bf16x8*)&Vt[wc * 32 + l31][j * 16 + g * 8];
  }
  // K, V ladders (normal orientation: D[t][e])
  f32x16 kacc = zero16(), vacc = zero16();
#pragma unroll
  for (int j = 0; j < 4; ++j) {
    kacc = MFMA32(xa[j], wkf[j], kacc);
    vacc = MFMA32(xa[j], wvf[j], vacc);
  }
  __syncthreads();   // bar1: weights consumed

  // stage K^T[e][t] / V^T[o][t], packed along t
#pragma unroll
  for (int q4 = 0; q4 < 4; ++q4) {
    u16x4 pk, pv;
#pragma unroll
    for (int i = 0; i < 4; ++i) {
      pk[i] = f2bs(elu1(kacc[q4 * 4 + i]));
      pv[i] = f2bs(vacc[q4 * 4 + i]);
    }
    *(u16x4*)&Kt[wc * 32 + l31][wr * 32 + 8 * q4 + 4 * g] = pk;
    *(u16x4*)&Vt[wc * 32 + l31][wr * 32 + 8 * q4 + 4 * g] = pv;
  }
  __syncthreads();   // bar2: K^T, V^T staged

  // KtV: D[e][o]; z = ones . K^T-cols (col-replicated)
  f32x16 sacc = zero16(), zacc = zero16();
  const bf16x8 one = ones8();
#pragma unroll
  for (int j = 0; j < 4; ++j) {
    bf16x8 aK = *(const bf16x8*)&Kt[wr * 32 + l31][j * 16 + g * 8];
    bf16x8 vB = *(const bf16x8*)&Vt[wc * 32 + l31][j * 16 + g * 8];
    sacc = MFMA32(aK, vB, sacc);
    bf16x8 kB = *(const bf16x8*)&Kt[wc * 32 + l31][j * 16 + g * 8];
    zacc = MFMA32(one, kB, zacc);
  }
  // stage mir[o][e] into Xb (packed along e): row o = wc*32+l31, cols e
#pragma unroll
  for (int q4 = 0; q4 < 4; ++q4) {
    u16x4 p;
#pragma unroll
    for (int i = 0; i < 4; ++i) p[i] = f2bs(sacc[q4 * 4 + i]);
    *(u16x4*)&Xb[wc * 32 + l31][wr * 32 + 8 * q4 + 4 * g] = p;
  }
  __syncthreads();   // bar3: mir staged

  // coalesced mir store
  unsigned short* mp = mir + (size_t)blk * 4096;
#pragma unroll
  for (int it = 0; it < 2; ++it) {
    int j = tid * 8 + it * 2048;
    int r = j >> 6, col = j & 63;
    *(uint4*)&mp[j] = *(const uint4*)&Xb[r][col];
  }
  if (w < 2 && g == 0)
    zmir[(size_t)blk * 64 + wc * 32 + l31] = f2bs(zacc[0]);
}

// ---------------------------------------------------------------------------
// K2: exclusive prefix over chunks — u32-vectorized (2 bf16/thread).
// grid = 64 bh * 9 groups (8 mir + 1 z).
// ---------------------------------------------------------------------------
__global__ __launch_bounds__(256) void k_prefix(
    unsigned short* __restrict__ mir, unsigned short* __restrict__ zmir)
{
  const int bh = blockIdx.x / 9, g = blockIdx.x % 9;
  const int tid = threadIdx.x;
  if (g < 8) {
    size_t base = (size_t)bh * 64 * 4096 + g * 512 + tid * 2;
    const unsigned short* mp = mir + base;
    unsigned v[64];
#pragma unroll
    for (int cc = 0; cc < 64; ++cc)
      v[cc] = *(const unsigned*)(mp + (size_t)cc * 4096);
    float c0 = 0.f, c1 = 0.f;
#pragma unroll
    for (int cc = 0; cc < 64; ++cc) {
      float f0 = b2f((unsigned short)(v[cc] & 0xffffu));
      float f1 = b2f((unsigned short)(v[cc] >> 16));
      v[cc] = (unsigned)f2bs(c0) | ((unsigned)f2bs(c1) << 16);
      c0 += f0; c1 += f1;
    }
    unsigned short* mw = mir + base;
#pragma unroll
    for (int cc = 0; cc < 64; ++cc)
      *(unsigned*)(mw + (size_t)cc * 4096) = v[cc];
  } else if (tid < 64) {
    size_t base = (size_t)bh * 64 * 64 + tid;
    unsigned short v[64];
#pragma unroll
    for (int cc = 0; cc < 64; ++cc) v[cc] = zmir[base + (size_t)cc * 64];
    float carry = 0.f;
#pragma unroll
    for (int cc = 0; cc < 64; ++cc) {
      float f = b2f(v[cc]);
      v[cc] = f2bs(carry);
      carry += f;
    }
#pragma unroll
    for (int cc = 0; cc < 64; ++cc) zmir[base + (size_t)cc * 64] = v[cc];
  }
}

// ---------------------------------------------------------------------------
// K3 (coalesced-staged, transposed-compute): per (b,h,chunk):
//   y = (Q Sprev + tril(Q K^T) V) / (q.zprev + rowsum(A) + eps)
// ---------------------------------------------------------------------------
__global__ __launch_bounds__(256) void k_y(
    const float* __restrict__ x, const unsigned short* __restrict__ wqT,
    const unsigned short* __restrict__ wkT, const unsigned short* __restrict__ wvT,
    const unsigned short* __restrict__ mir, const unsigned short* __restrict__ zmir,
    unsigned short* __restrict__ y)
{
  __shared__ __align__(16) unsigned short Xb[64][72];   // x -> mir[o][e]
  __shared__ __align__(16) unsigned short Qb[64][72];   // WqT -> Q[t][e] -> A[t][s]
  __shared__ __align__(16) unsigned short Kb[64][72];   // WkT -> K[s][e] -> y[t][o]
  __shared__ __align__(16) unsigned short Vt[64][72];   // WvT -> V^T[o][t]

  const int tid = threadIdx.x, blk = blockIdx.x;
  const int c = blk & 63, bh = blk >> 6, h = bh & 15, b = bh >> 4;
  const int l = tid & 63, w = tid >> 6;
  const int wr = w >> 1, wc = w & 1;
  const int l31 = l & 31, g = l >> 5;
  const size_t sblk = (size_t)blk;

  // --- early coalesced mir load -> regs (hides under staging) ---
  const unsigned short* mp = mir + sblk * 4096;
  uint4 mreg[2];
#pragma unroll
  for (int it = 0; it < 2; ++it)
    mreg[it] = *(const uint4*)&mp[tid * 8 + it * 2048];
  // z splat fragments (lane-group-uniform 16B loads)
  const unsigned short* zp = zmir + sblk * 64;
  bf16x8 zf[4];
#pragma unroll
  for (int j = 0; j < 4; ++j)
    zf[j] = *(const bf16x8*)(zp + j * 16 + g * 8);

  // --- coalesced weight loads -> LDS ---
  const unsigned short* wqp = wqT + h * 4096;
  const unsigned short* wkp = wkT + h * 4096;
  const unsigned short* wvp = wvT + h * 4096;
#pragma unroll
  for (int it = 0; it < 2; ++it) {
    int j = tid * 8 + it * 2048;
    int r = j >> 6, col = j & 63;
    *(uint4*)&Qb[r][col] = *(const uint4*)&wqp[j];
    *(uint4*)&Kb[r][col] = *(const uint4*)&wkp[j];
    *(uint4*)&Vt[r][col] = *(const uint4*)&wvp[j];
  }
  // --- coalesced x load + cvt -> Xb ---
  const float* xbase = x + ((size_t)(b * Sv + c * 64)) * 1024 + h * 64;
#pragma unroll
  for (int it = 0; it < 4; ++it) {
    int u = tid + it * 256;
    int r = u >> 4, seg = u & 15;
    float4 f = *(const float4*)(xbase + (size_t)r * 1024 + seg * 4);
    u16x4 p; p[0] = f2bs(f.x); p[1] = f2bs(f.y); p[2] = f2bs(f.z); p[3] = f2bs(f.w);
    *(u16x4*)&Xb[r][seg * 4] = p;
  }
  __syncthreads();   // bar0: staging done

  // fragments from LDS
  bf16x8 xa[4], wqf[4], wkf[4], wvf[4];
#pragma unroll
  for (int j = 0; j < 4; ++j) {
    xa[j]  = *(const bf16x8*)&Xb[wr * 32 + l31][j * 16 + g * 8];
    wqf[j] = *(const bf16x8*)&Qb[wc * 32 + l31][j * 16 + g * 8];
    wkf[j] = *(const bf16x8*)&Kb[wc * 32 + l31][j * 16 + g * 8];
    wvf[j] = *(const bf16x8*)&Vt[wc * 32 + l31][j * 16 + g * 8];
  }
  // Q^T, K^T ladders (transposed: D[e][t] / D[e][s]); V ladder (normal D[t][o])
  f32x16 qacc = zero16(), kacc = zero16(), vacc = zero16();
#pragma unroll
  for (int j = 0; j < 4; ++j) {
    qacc = MFMA32(wqf[j], xa[j], qacc);
    kacc = MFMA32(wkf[j], xa[j], kacc);
    vacc = MFMA32(xa[j], wvf[j], vacc);
  }
  __syncthreads();   // bar1: weights + x consumed

  // stage Q[t][e], K[s][e], V^T[o][t] (all packed); mir regs -> Xb[o][e]
#pragma unroll
  for (int q4 = 0; q4 < 4; ++q4) {
    u16x4 pq, pk, pv;
#pragma unroll
    for (int i = 0; i < 4; ++i) {
      pq[i] = f2bs(elu1(qacc[q4 * 4 + i]));
      pk[i] = f2bs(elu1(kacc[q4 * 4 + i]));
      pv[i] = f2bs(vacc[q4 * 4 + i]);
    }
    *(u16x4*)&Qb[wr * 32 + l31][wc * 32 + 8 * q4 + 4 * g] = pq;
    *(u16x4*)&Kb[wr * 32 + l31][wc * 32 + 8 * q4 + 4 * g] = pk;
    *(u16x4*)&Vt[wc * 32 + l31][wr * 32 + 8 * q4 + 4 * g] = pv;
  }
#pragma unroll
  for (int it = 0; it < 2; ++it) {
    int j = tid * 8 + it * 2048;
    int r = j >> 6, col = j & 63;
    *(uint4*)&Xb[r][col] = mreg[it];
  }
  __syncthreads();   // bar2: Q,K,V^T,mir staged

  // qa fragments (rows t = wr*32 + l31, full e)
  bf16x8 qa[4];
#pragma unroll
  for (int j = 0; j < 4; ++j)
    qa[j] = *(const bf16x8*)&Qb[wr * 32 + l31][j * 16 + g * 8];

  // y^T (QS): D[o][t] = MFMA(S^T-rows, Q); den: MFMA(z-splat, Q); A^T: MFMA(K, Q)
  f32x16 aacc = zero16(), nacc = zero16(), dacc = zero16();
#pragma unroll
  for (int j = 0; j < 4; ++j) {
    bf16x8 sA = *(const bf16x8*)&Xb[wc * 32 + l31][j * 16 + g * 8];
    nacc = MFMA32(sA, qa[j], nacc);
    dacc = MFMA32(zf[j], qa[j], dacc);
  }
  if (w != 1) {  // wave 1 (t<32, s>=32) strictly upper -> A quadrant = 0
#pragma unroll
    for (int j = 0; j < 4; ++j) {
      bf16x8 kA = *(const bf16x8*)&Kb[wc * 32 + l31][j * 16 + g * 8];
      aacc = MFMA32(kA, qa[j], aacc);
    }
    if (w == 0 || w == 3) {  // diagonal: zero s > t (s=pattern, t=l31)
#pragma unroll
      for (int r = 0; r < 16; ++r)
        if ((r & 3) + 8 * (r >> 2) + 4 * g > l31) aacc[r] = 0.f;
    }
  }
  __syncthreads();   // bar3: Qb(Q) / Kb(K) consumed

  // stage A[t][s] packed
  if (w != 1) {
#pragma unroll
    for (int q4 = 0; q4 < 4; ++q4) {
      u16x4 p;
#pragma unroll
      for (int i = 0; i < 4; ++i) p[i] = f2bs(aacc[q4 * 4 + i]);
      *(u16x4*)&Qb[wr * 32 + l31][wc * 32 + 8 * q4 + 4 * g] = p;
    }
  }
  __syncthreads();   // bar4: A staged

  // y^T += V^T-rows . A ; den += ones . A (row-replicated rowsum)
  const bf16x8 one = ones8();
  const int jmax = (wr == 0) ? 2 : 4;   // t<32 -> only s<32 contributes
#pragma unroll
  for (int j = 0; j < 4; ++j) {
    if (j >= jmax) break;
    bf16x8 aA = *(const bf16x8*)&Qb[wr * 32 + l31][j * 16 + g * 8];
    bf16x8 vA = *(const bf16x8*)&Vt[wc * 32 + l31][j * 16 + g * 8];
    nacc = MFMA32(vA, aA, nacc);
    dacc = MFMA32(one, aA, dacc);
  }

  // ONE rcp per lane (dacc row-replicated; den of row t = wr*32+l31)
  const float invd = __builtin_amdgcn_rcpf(dacc[0] + 1e-6f);
  // stage y[t][o] packed — wave-private quadrant
#pragma unroll
  for (int q4 = 0; q4 < 4; ++q4) {
    u16x4 p;
#pragma unroll
    for (int i = 0; i < 4; ++i) p[i] = f2bs(nacc[q4 * 4 + i] * invd);
    *(u16x4*)&Kb[wr * 32 + l31][wc * 32 + 8 * q4 + 4 * g] = p;
  }
  // wave-private coalesced store (in-wave DS order; NO barrier)
  unsigned short* yb = y + ((size_t)(b * Sv + c * 64)) * 1024 + h * 64;
#pragma unroll
  for (int i = 0; i < 2; ++i) {
    int unit = l + i * 64;
    int t_loc = unit >> 2, seg = unit & 3;
    uint4 q = *(const uint4*)&Kb[wr * 32 + t_loc][wc * 32 + seg * 8];
    *(uint4*)&yb[(size_t)(wr * 32 + t_loc) * 1024 + wc * 32 + seg * 8] = q;
  }
}

// ---------------------------------------------------------------------------
// K4 (coalesced-staged 32x32 MFMA): out = y @ Wp. 64 rows/block, 4 waves.
// K=1024 split into 8 x 128-col LDS-staged tiles; dual accumulator chains.
// ---------------------------------------------------------------------------
__global__ __launch_bounds__(256) void k_proj(
    const unsigned short* __restrict__ y, const unsigned short* __restrict__ wpT,
    float* __restrict__ out)
{
  __shared__ __align__(16) unsigned short Ys[64][136];
  __shared__ __align__(16) unsigned short Ws[64][136];

  const int tid = threadIdx.x, bid = blockIdx.x;
  const int l = tid & 63, w = tid >> 6;
  const int wr = w >> 1, wc = w & 1;
  const int l31 = l & 31, g = l >> 5;
  const size_t row0 = (size_t)bid * 64;

  f32x16 acc0 = zero16(), acc1 = zero16();
#pragma unroll 1
  for (int kc = 0; kc < 8; ++kc) {
    __syncthreads();   // prev tiles consumed
#pragma unroll
    for (int it = 0; it < 4; ++it) {
      int u = tid + it * 256;
      int r = u >> 4, seg = u & 15;
      *(uint4*)&Ys[r][seg * 8] =
          *(const uint4*)&y[(row0 + r) * 1024 + kc * 128 + seg * 8];
      *(uint4*)&Ws[r][seg * 8] =
          *(const uint4*)&wpT[(size_t)r * 1024 + kc * 128 + seg * 8];
    }
    __syncthreads();   // tiles staged
#pragma unroll
    for (int jj = 0; jj < 8; jj += 2) {
      bf16x8 a0 = *(const bf16x8*)&Ys[wr * 32 + l31][jj * 16 + g * 8];
      bf16x8 b0 = *(const bf16x8*)&Ws[wc * 32 + l31][jj * 16 + g * 8];
      acc0 = MFMA32(a0, b0, acc0);
      bf16x8 a1 = *(const bf16x8*)&Ys[wr * 32 + l31][(jj + 1) * 16 + g * 8];
      bf16x8 b1 = *(const bf16x8*)&Ws[wc * 32 + l31][(jj + 1) * 16 + g * 8];
      acc1 = MFMA32(a1, b1, acc1);
    }
  }
  float* op = out + (row0 + wr * 32) * 64 + wc * 32;
#pragma unroll
  for (int r = 0; r < 16; ++r)
    op[(size_t)((r & 3) + 8 * (r >> 2) + 4 * g) * 64 + l31] = acc0[r] + acc1[r];
}

// ---------------------------------------------------------------------------
extern "C" void kernel_launch(void* const* d_in, const int* in_sizes, int n_in,
                              void* d_out, int out_size, void* d_ws, size_t ws_size,
                              hipStream_t stream)
{
  const float* x  = (const float*)d_in[0];
  const float* Wq = (const float*)d_in[1];
  const float* Wk = (const float*)d_in[2];
  const float* Wv = (const float*)d_in[3];
  const float* Wp = (const float*)d_in[4];
  float* out = (float*)d_out;

  // ws layout: mir bf16 33.55 MB | zmir bf16 0.52 | wqT/wkT/wvT/wpT 0.52 |
  //            y bf16 [16384][1024] 33.55 MB      (total ~68 MB)
  unsigned short* mir = (unsigned short*)d_ws;
  unsigned short* zmir = mir + 16777216;
  unsigned short* wqT = zmir + 262144;
  unsigned short* wkT = wqT + 65536;
  unsigned short* wvT = wkT + 65536;
  unsigned short* wpT = wvT + 65536;
  unsigned short* yb  = wpT + 65536;

  hipLaunchKernelGGL(k_prep_w, dim3(80), dim3(256), 0, stream,
                     Wq, Wk, Wv, Wp, wqT, wkT, wvT, wpT);
  hipLaunchKernelGGL(k_chunk_state, dim3(BHv * NCv), dim3(256), 0, stream,
                     x, wkT, wvT, mir, zmir);
  hipLaunchKernelGGL(k_prefix, dim3(BHv * 9), dim3(256), 0, stream, mir, zmir);
  hipLaunchKernelGGL(k_y, dim3(BHv * NCv), dim3(256), 0, stream,
                     x, wqT, wkT, wvT, mir, zmir, yb);
  hipLaunchKernelGGL(k_proj, dim3((Bv * Sv) / 64), dim3(256), 0, stream,
                     yb, wpT, out);
}